// Round 2
// baseline (18553.737 us; speedup 1.0000x reference)
//
#include <hip/hip_runtime.h>
#include <hip/hip_bf16.h>
#include <math.h>

// ---------------------------------------------------------------------------
// DeepTemplateMatchingModule — fp32 baseline, round 2.
// Round-1 failure: ws_size < 371 MiB -> early return -> zero output.
// This round: adaptive chunking (C samples through the conv trunk at a time),
// ping-pong conv scratch, gib/Sb aliased into the conv arena. Min ws: ~32 MiB.
// ---------------------------------------------------------------------------

#define DEVI static __device__ __forceinline__

DEVI float fsig(float x)   { return 1.f / (1.f + __expf(-x)); }
DEVI float ftanh_(float x) { return 2.f / (1.f + __expf(-2.f * x)) - 1.f; }

// ---------------- pack: x0c[nl][t][c] = (n<16?eval:template)[n%16][c][t] ----
__global__ void pack_kernel(const float* __restrict__ ev,
                            const float* __restrict__ tmpl,
                            float* __restrict__ x0, int n0)
{
    const int nl = blockIdx.z;
    const int n  = n0 + nl;
    const int t0 = blockIdx.x * 32;
    const int c0 = blockIdx.y * 32;
    const float* src = (n < 16) ? (ev + n * 65536) : (tmpl + (n - 16) * 65536);
    __shared__ float tile[32][33];
    const int tx = threadIdx.x, ty = threadIdx.y; // (32,8)
#pragma unroll
    for (int k = 0; k < 4; k++) {
        int cl = ty + 8 * k;
        tile[cl][tx] = src[(c0 + cl) * 512 + t0 + tx];
    }
    __syncthreads();
#pragma unroll
    for (int k = 0; k < 4; k++) {
        int tl = ty + 8 * k;
        x0[(nl * 512 + t0 + tl) * 128 + c0 + tx] = tile[tx][tl];
    }
}

// ---------------- generic 5x5 VALID conv (NCHW), 4 output rows per block ----
template<int CI, int CO, int CO_PER, int W_T, int H_IN, int W_IN>
__global__ void conv5x5_kernel(const float* __restrict__ in,
                               const float* __restrict__ wgt,
                               const float* __restrict__ bias,
                               float* __restrict__ out)
{
    constexpr int H_OUT = H_IN - 4;
    constexpr int W_OUT = W_IN - 4;
    constexpr int HALO  = W_T + 4;

    const int h0  = blockIdx.x * 4;
    const int w0  = blockIdx.y * W_T;
    const int n   = blockIdx.z;
    const int tid = threadIdx.x;
    const int wl  = tid & 63;
    const int cg  = tid >> 6;

    __shared__ float tin[8 * 68];
    __shared__ float tw[CO * 25];

    float acc[CO_PER][4];
#pragma unroll
    for (int j = 0; j < CO_PER; j++)
#pragma unroll
        for (int hh = 0; hh < 4; hh++) acc[j][hh] = 0.f;

    for (int ci = 0; ci < CI; ci++) {
        __syncthreads();
        const float* ibase = in + ((n * CI + ci) * H_IN + h0) * W_IN + w0;
        for (int idx = tid; idx < 8 * HALO; idx += 256) {
            int r = idx / HALO, cc = idx - r * HALO;
            tin[r * 68 + cc] = ibase[r * W_IN + cc];
        }
        const float* wbase = wgt + ci * 25;
        for (int idx = tid; idx < CO * 25; idx += 256) {
            int co = idx / 25, tap = idx - co * 25;
            tw[idx] = wbase[co * (CI * 25) + tap];
        }
        __syncthreads();
#pragma unroll
        for (int kh = 0; kh < 5; kh++) {
#pragma unroll
            for (int kw = 0; kw < 5; kw++) {
                float iv[4];
#pragma unroll
                for (int hh = 0; hh < 4; hh++)
                    iv[hh] = tin[(hh + kh) * 68 + wl + kw];
#pragma unroll
                for (int j = 0; j < CO_PER; j++) {
                    float wv = tw[(cg * CO_PER + j) * 25 + kh * 5 + kw];
#pragma unroll
                    for (int hh = 0; hh < 4; hh++)
                        acc[j][hh] = fmaf(wv, iv[hh], acc[j][hh]);
                }
            }
        }
    }

    if (wl < W_T) {
#pragma unroll
        for (int j = 0; j < CO_PER; j++) {
            int co = cg * CO_PER + j;
            float bv = bias[co];
#pragma unroll
            for (int hh = 0; hh < 4; hh++)
                out[((n * CO + co) * H_OUT + h0 + hh) * W_OUT + w0 + wl] =
                    acc[j][hh] + bv;
        }
    }
}

// ---------------- maxpool (5,2)/(1,2): (C,64,500,116)->(C,64,496,58) --------
__global__ void pool_kernel(const float* __restrict__ in,
                            float* __restrict__ out)
{
    int idx = blockIdx.x * 256 + threadIdx.x; // total C*64*496*58 exact
    int j = idx % 58;
    int tmp = idx / 58;
    int s = tmp % 496;
    tmp /= 496;
    int c  = tmp & 63;
    int nl = tmp >> 6;
    const float* base = in + ((nl * 64 + c) * 500 + s) * 116 + 2 * j;
    float m = -1e30f;
#pragma unroll
    for (int r = 0; r < 5; r++) {
        m = fmaxf(m, base[r * 116]);
        m = fmaxf(m, base[r * 116 + 1]);
    }
    out[idx] = m;
}

// ---------------- lin1: xb[n][s][o] = pooled_n[s*3712+f] . W[o][f] + b ------
__global__ void lin1_kernel(const float* __restrict__ pooled,
                            const float* __restrict__ W,
                            const float* __restrict__ bvec,
                            float* __restrict__ xout, int n0)
{
    const int s0 = blockIdx.x * 32;
    const int nl = blockIdx.y;
    const int t  = threadIdx.x;
    const int o  = t & 63, sg = t >> 6;
    __shared__ __align__(16) float As[32 * 128];
    __shared__ float Ws[128 * 65];
    float acc[8];
#pragma unroll
    for (int i = 0; i < 8; i++) acc[i] = 0.f;

    const float* arow = pooled + (size_t)nl * 1841152;
    for (int fc = 0; fc < 3712; fc += 128) {
        __syncthreads();
        for (int idx = t; idx < 4096; idx += 256) {
            int r = idx >> 7, c = idx & 127;
            int s = s0 + r;
            As[idx] = (s < 496) ? arow[s * 3712 + fc + c] : 0.f;
        }
        for (int idx = t; idx < 8192; idx += 256) {
            int oo = idx >> 7, c = idx & 127;
            Ws[c * 65 + oo] = W[oo * 3712 + fc + c];
        }
        __syncthreads();
        for (int f = 0; f < 128; f += 4) {
            float w0 = Ws[(f + 0) * 65 + o];
            float w1 = Ws[(f + 1) * 65 + o];
            float w2 = Ws[(f + 2) * 65 + o];
            float w3 = Ws[(f + 3) * 65 + o];
#pragma unroll
            for (int i = 0; i < 8; i++) {
                float4 a = *((const float4*)&As[(sg * 8 + i) * 128 + f]);
                acc[i] = fmaf(a.x, w0, acc[i]);
                acc[i] = fmaf(a.y, w1, acc[i]);
                acc[i] = fmaf(a.z, w2, acc[i]);
                acc[i] = fmaf(a.w, w3, acc[i]);
            }
        }
    }
    const int n = n0 + nl;
#pragma unroll
    for (int i = 0; i < 8; i++) {
        int s = s0 + sg * 8 + i;
        if (s < 496) xout[(n * 496 + s) * 64 + o] = acc[i] + bvec[o];
    }
}

// ---------------- gi = x @ W_ih^T + b_ih : rows 0..15871, 192 outputs -------
__global__ void gi_kernel(const float* __restrict__ x,
                          const float* __restrict__ Wih,
                          const float* __restrict__ bih,
                          float* __restrict__ gi)
{
    const int r0 = blockIdx.x * 16;
    const int j  = threadIdx.x; // 192 threads
    __shared__ float xl[16 * 64];
    float w[64];
#pragma unroll
    for (int d = 0; d < 64; d++) w[d] = Wih[j * 64 + d];
    const float bj = bih[j];
    for (int idx = j; idx < 1024; idx += 192) xl[idx] = x[r0 * 64 + idx];
    __syncthreads();
    for (int s = 0; s < 16; s++) {
        float a = bj;
#pragma unroll
        for (int d = 0; d < 64; d++) a = fmaf(w[d], xl[s * 64 + d], a);
        gi[(size_t)(r0 + s) * 192 + j] = a;
    }
}

// ---------------- chunk-parallel GRU. 512 blocks x 64 threads. -------------
__global__ __launch_bounds__(64, 1) void gru_kernel(
    const float* __restrict__ gi, const float* __restrict__ Whh,
    const float* __restrict__ bhh, float* __restrict__ Eo,
    float* __restrict__ To)
{
    const int c  = blockIdx.x;
    const int br = c >> 8;
    const int q  = c & 255;
    const int i  = threadIdx.x;
    const float* gb = gi + (size_t)br * 7936 * 192;
    float* out = br ? To : Eo;

    float wr[64], wz[64], wn[64];
#pragma unroll
    for (int k = 0; k < 64; k++) wr[k] = Whh[i * 64 + k];
#pragma unroll
    for (int k = 0; k < 64; k++) wz[k] = Whh[(64 + i) * 64 + k];
#pragma unroll
    for (int k = 0; k < 64; k++) wn[k] = Whh[(128 + i) * 64 + k];
    const float bhr = bhh[i], bhz = bhh[64 + i], bhn = bhh[128 + i];

    __shared__ __align__(16) float hs[64];
    float h[64];
#pragma unroll
    for (int k = 0; k < 64; k++) h[k] = 0.f;
    float hown = 0.f;

    const int cs  = q * 31;
    int start = cs - 96;
    if (start < 0) start = 0;
    const int end = cs + 31;

    float pr[4], pz[4], pn[4];
#pragma unroll
    for (int u = 0; u < 4; u++) {
        int s = start + u;
        if (s < end) {
            const float* g = gb + (size_t)s * 192;
            pr[u] = g[i]; pz[u] = g[64 + i]; pn[u] = g[128 + i];
        } else { pr[u] = 0.f; pz[u] = 0.f; pn[u] = 0.f; }
    }

    int s = start;
    while (s < end) {
#pragma unroll
        for (int u = 0; u < 4; u++) {
            if (s < end) {
                float gr = pr[u], gz = pz[u], gn = pn[u];
                int sp = s + 4;
                if (sp < end) {
                    const float* g = gb + (size_t)sp * 192;
                    pr[u] = g[i]; pz[u] = g[64 + i]; pn[u] = g[128 + i];
                }
                float ar = bhr, az = bhz, an = bhn;
#pragma unroll
                for (int k = 0; k < 64; k++) {
                    ar = fmaf(wr[k], h[k], ar);
                    az = fmaf(wz[k], h[k], az);
                    an = fmaf(wn[k], h[k], an);
                }
                float r  = fsig(gr + ar);
                float z  = fsig(gz + az);
                float nv = ftanh_(gn + r * an);
                float hn = (1.f - z) * nv + z * hown;
                hown = hn;
                hs[i] = hn;
                __syncthreads();
#pragma unroll
                for (int k = 0; k < 16; k++) {
                    float4 v = ((const float4*)hs)[k];
                    h[4 * k + 0] = v.x; h[4 * k + 1] = v.y;
                    h[4 * k + 2] = v.z; h[4 * k + 3] = v.w;
                }
                __syncthreads();
                if (s >= cs) out[(size_t)s * 64 + i] = hn;
                s++;
            }
        }
    }
}

// ---------------- scores[b][m][n] = E[b][m] . Tm[b][n] ----------------------
__global__ void scores_kernel(const float* __restrict__ E,
                              const float* __restrict__ Tm,
                              float* __restrict__ S)
{
    const int b  = blockIdx.z;
    const int m0 = blockIdx.y * 32;
    const int n0 = blockIdx.x * 64;
    const int t  = threadIdx.x;
    const int nl = t & 63, mg = t >> 6;
    __shared__ float El[32 * 64];
    __shared__ float Tms[64 * 65];

    for (int idx = t; idx < 2048; idx += 256) {
        int r = idx >> 6, d = idx & 63;
        int m = m0 + r;
        El[idx] = (m < 496) ? E[((size_t)b * 496 + m) * 64 + d] : 0.f;
    }
    for (int idx = t; idx < 4096; idx += 256) {
        int r = idx >> 6, d = idx & 63;
        int n = n0 + r;
        Tms[d * 65 + r] = (n < 496) ? Tm[((size_t)b * 496 + n) * 64 + d] : 0.f;
    }
    __syncthreads();

    float acc[8];
#pragma unroll
    for (int j = 0; j < 8; j++) acc[j] = 0.f;
#pragma unroll 4
    for (int d = 0; d < 64; d++) {
        float tv = Tms[d * 65 + nl];
#pragma unroll
        for (int j = 0; j < 8; j++)
            acc[j] = fmaf(El[(mg * 8 + j) * 64 + d], tv, acc[j]);
    }
    int n = n0 + nl;
    if (n < 496) {
#pragma unroll
        for (int j = 0; j < 8; j++) {
            int m = m0 + mg * 8 + j;
            if (m < 496) S[((size_t)b * 496 + m) * 496 + n] = acc[j];
        }
    }
}

// ---------------- softmax over m (axis=1) for each (b, n); in-place ---------
__global__ void colsoftmax_kernel(float* __restrict__ S)
{
    const int b = blockIdx.y;
    const int n = blockIdx.x * 64 + threadIdx.x;
    if (n >= 496) return;
    float* base = S + (size_t)b * 246016 + n;
    float m = -1e30f;
#pragma unroll 4
    for (int mm = 0; mm < 496; mm++) m = fmaxf(m, base[mm * 496]);
    float sum = 0.f;
#pragma unroll 4
    for (int mm = 0; mm < 496; mm++) {
        float e = __expf(base[mm * 496] - m);
        base[mm * 496] = e;
        sum += e;
    }
    float inv = 1.f / sum;
#pragma unroll 4
    for (int mm = 0; mm < 496; mm++) base[mm * 496] *= inv;
}

// ---------------- Tp[b][m][d] = sum_n A[b][m][n] * Tm[b][n][d] --------------
__global__ void tp_kernel(const float* __restrict__ A,
                          const float* __restrict__ Tm,
                          float* __restrict__ Tp)
{
    const int b  = blockIdx.y;
    const int m0 = blockIdx.x * 32;
    const int t  = threadIdx.x;
    const int d  = t & 63, mg = t >> 6;
    __shared__ float As[32 * 128];
    __shared__ float Ts[128 * 64];
    float acc[8];
#pragma unroll
    for (int j = 0; j < 8; j++) acc[j] = 0.f;

    for (int nc = 0; nc < 512; nc += 128) {
        __syncthreads();
        for (int idx = t; idx < 4096; idx += 256) {
            int r = idx >> 7, cc = idx & 127;
            int m = m0 + r, n = nc + cc;
            As[idx] = (m < 496 && n < 496)
                          ? A[((size_t)b * 496 + m) * 496 + n] : 0.f;
        }
        for (int idx = t; idx < 8192; idx += 256) {
            int r = idx >> 6, dd = idx & 63;
            int n = nc + r;
            Ts[idx] = (n < 496) ? Tm[((size_t)b * 496 + n) * 64 + dd] : 0.f;
        }
        __syncthreads();
#pragma unroll 4
        for (int nn = 0; nn < 128; nn++) {
            float tv = Ts[nn * 64 + d];
#pragma unroll
            for (int j = 0; j < 8; j++)
                acc[j] = fmaf(As[(mg * 8 + j) * 128 + nn], tv, acc[j]);
        }
    }
#pragma unroll
    for (int j = 0; j < 8; j++) {
        int m = m0 + mg * 8 + j;
        if (m < 496) Tp[((size_t)b * 496 + m) * 64 + d] = acc[j];
    }
}

// ---------------- att softmax over s + rep[b][d] = sum_s att*|Tp-E| ---------
__global__ void attrep_kernel(const float* __restrict__ E,
                              const float* __restrict__ Tp,
                              const float* __restrict__ attw,
                              const float* __restrict__ attb,
                              float* __restrict__ rep)
{
    const int b = blockIdx.x;
    const int t = threadIdx.x; // 256
    __shared__ float aw[64];
    __shared__ float lg[496];
    __shared__ float att[496];
    __shared__ float redm[4], reds[4];
    __shared__ float part[256];

    if (t < 64) aw[t] = attw[t];
    __syncthreads();
    for (int s = t; s < 496; s += 256) {
        const float* Er = E + ((size_t)b * 496 + s) * 64;
        float a = 0.f;
#pragma unroll
        for (int dd = 0; dd < 64; dd++) a = fmaf(Er[dd], aw[dd], a);
        lg[s] = a + attb[0];
    }
    __syncthreads();
    float m = -1e30f;
    for (int s = t; s < 496; s += 256) m = fmaxf(m, lg[s]);
    for (int off = 32; off > 0; off >>= 1)
        m = fmaxf(m, __shfl_xor(m, off, 64));
    if ((t & 63) == 0) redm[t >> 6] = m;
    __syncthreads();
    m = fmaxf(fmaxf(redm[0], redm[1]), fmaxf(redm[2], redm[3]));
    float sum = 0.f;
    for (int s = t; s < 496; s += 256) {
        float e = __expf(lg[s] - m);
        att[s] = e;
        sum += e;
    }
    for (int off = 32; off > 0; off >>= 1) sum += __shfl_xor(sum, off, 64);
    if ((t & 63) == 0) reds[t >> 6] = sum;
    __syncthreads();
    float inv = 1.f / (reds[0] + reds[1] + reds[2] + reds[3]);

    const int d = t & 63, sg = t >> 6;
    float p = 0.f;
    for (int k = 0; k < 124; k++) {
        int s = sg + 4 * k;
        size_t o = ((size_t)b * 496 + s) * 64 + d;
        p = fmaf(att[s] * inv, fabsf(Tp[o] - E[o]), p);
    }
    part[t] = p;
    __syncthreads();
    if (t < 64)
        rep[b * 64 + t] = part[t] + part[64 + t] + part[128 + t] + part[192 + t];
}

// ---------------- tail MLP: relu(rep) -> relu(lin3) -> cls ------------------
__global__ void mlp_kernel(const float* __restrict__ rep,
                           const float* __restrict__ W3,
                           const float* __restrict__ b3,
                           const float* __restrict__ Wc,
                           const float* __restrict__ bc,
                           float* __restrict__ out)
{
    const int b = blockIdx.x;
    const int t = threadIdx.x; // 128
    __shared__ float hr[64];
    __shared__ float h2[128];
    if (t < 64) hr[t] = fmaxf(rep[b * 64 + t], 0.f);
    __syncthreads();
    float a = b3[t];
#pragma unroll
    for (int d = 0; d < 64; d++) a = fmaf(W3[t * 64 + d], hr[d], a);
    h2[t] = fmaxf(a, 0.f);
    __syncthreads();
    if (t < 2) {
        float o = bc[t];
        for (int k = 0; k < 128; k++) o = fmaf(Wc[t * 128 + k], h2[k], o);
        out[b * 2 + t] = o;
    }
}

// ---------------------------------------------------------------------------
extern "C" void kernel_launch(void* const* d_in, const int* in_sizes, int n_in,
                              void* d_out, int out_size, void* d_ws,
                              size_t ws_size, hipStream_t stream)
{
    const float* ev   = (const float*)d_in[0];
    const float* tmpl = (const float*)d_in[1];
    const float* w1   = (const float*)d_in[2];
    const float* b1   = (const float*)d_in[3];
    const float* w2   = (const float*)d_in[4];
    const float* b2   = (const float*)d_in[5];
    const float* w3   = (const float*)d_in[6];
    const float* b3   = (const float*)d_in[7];
    const float* l1w  = (const float*)d_in[8];
    const float* l1b  = (const float*)d_in[9];
    const float* wih  = (const float*)d_in[10];
    const float* whh  = (const float*)d_in[11];
    const float* bih  = (const float*)d_in[12];
    const float* bhh  = (const float*)d_in[13];
    const float* attw = (const float*)d_in[14];
    const float* attb = (const float*)d_in[15];
    const float* l3w  = (const float*)d_in[16];
    const float* l3b  = (const float*)d_in[17];
    const float* clw  = (const float*)d_in[18];
    const float* clb  = (const float*)d_in[19];

    // ---- persistent region (floats) ----
    // xb 1,015,808 | Eb 507,904 | Tb 507,904 | Tpb 507,904 | repb 1,024
    float* ws = (float*)d_ws;
    float* xb   = ws;
    float* Eb   = xb + 1015808ull;
    float* Tb   = Eb + 507904ull;
    float* Tpb  = Tb + 507904ull;
    float* repb = Tpb + 507904ull;
    float* arena = repb + 1024ull;
    const size_t PERSIST = 2540544ull;

    // ---- pick largest chunk size C that fits ws_size ----
    // conv scratch (ping-pong): bufA = C*1,935,360 (x0c/c2/pooled),
    //                           bufB = C*3,712,000 (c1/c3)
    // arena also hosts (sequentially): gib 3,047,424 and Sb 3,936,256.
    const int cand[6] = {32, 16, 8, 4, 2, 1};
    int C = 0;
    for (int ci = 0; ci < 6; ci++) {
        size_t a = (size_t)cand[ci] * 5647360ull;
        if (a < 3936256ull) a = 3936256ull;
        if ((PERSIST + a + 256ull) * sizeof(float) <= ws_size) { C = cand[ci]; break; }
    }
    if (C == 0) return; // ws too small even for minimal plan

    float* bufA = arena;                              // C*1,935,360
    float* bufB = arena + (size_t)C * 1935360ull;     // C*3,712,000
    float* gib  = arena;                              // 3,047,424 (after conv)
    float* Sb   = arena;                              // 3,936,256 (after gru)

    // ---- conv trunk + lin1, chunked ----
    for (int n0 = 0; n0 < 32; n0 += C) {
        float* x0c = bufA;
        float* c1  = bufB;
        float* c2  = bufA;
        float* c3  = bufB;
        float* pl  = bufA;
        pack_kernel<<<dim3(16, 4, C), dim3(32, 8), 0, stream>>>(ev, tmpl, x0c, n0);
        conv5x5_kernel<1, 16, 4, 62, 512, 128>
            <<<dim3(127, 2, C), 256, 0, stream>>>(x0c, w1, b1, c1);
        conv5x5_kernel<16, 32, 8, 60, 508, 124>
            <<<dim3(126, 2, C), 256, 0, stream>>>(c1, w2, b2, c2);
        conv5x5_kernel<32, 64, 16, 58, 504, 120>
            <<<dim3(125, 2, C), 256, 0, stream>>>(c2, w3, b3, c3);
        pool_kernel<<<C * 7192, 256, 0, stream>>>(c3, pl);
        lin1_kernel<<<dim3(16, C), 256, 0, stream>>>(pl, l1w, l1b, xb, n0);
    }

    // ---- GRU input gates, then chunk-parallel GRU scan ----
    gi_kernel<<<992, 192, 0, stream>>>(xb, wih, bih, gib);
    gru_kernel<<<512, 64, 0, stream>>>(gib, whh, bhh, Eb, Tb);

    // ---- alignment: scores -> softmax over m -> Tp ----
    scores_kernel<<<dim3(8, 16, 16), 256, 0, stream>>>(Eb, Tb, Sb);
    colsoftmax_kernel<<<dim3(8, 16), 64, 0, stream>>>(Sb);
    tp_kernel<<<dim3(16, 16), 256, 0, stream>>>(Sb, Tb, Tpb);

    // ---- attention + representation, tail MLP ----
    attrep_kernel<<<16, 256, 0, stream>>>(Eb, Tpb, attw, attb, repb);
    mlp_kernel<<<16, 128, 0, stream>>>(repb, l3w, l3b, clw, clb,
                                       (float*)d_out);
}

// Round 3
// 1334.646 us; speedup vs baseline: 13.9016x; 13.9016x over previous
//
#include <hip/hip_runtime.h>
#include <hip/hip_bf16.h>
#include <math.h>

// ---------------------------------------------------------------------------
// DeepTemplateMatchingModule — round 3: bf16 MFMA trunk.
// conv2/conv3/lin1 -> implicit-GEMM bf16 MFMA (16x16x32). conv1 fp32 -> NHWC
// bf16. pool = vertical+pair max (NHWC) then LDS transpose to NCHW-flat bf16.
// lin1 uses k'=r*64+j zero-padded K=4096, k-split x4 + atomicAdd into xb.
// GRU & tail stay fp32 (round-2 verified, absmax was 0.0).
// ---------------------------------------------------------------------------

#define DEVI static __device__ __forceinline__
typedef __attribute__((ext_vector_type(8))) short short8;
typedef __attribute__((ext_vector_type(4))) float f32x4;
typedef unsigned short ushort_t;

DEVI float fsig(float x)   { return 1.f / (1.f + __expf(-x)); }
DEVI float ftanh_(float x) { return 2.f / (1.f + __expf(-2.f * x)) - 1.f; }
DEVI float bf2f(ushort_t u) { union { unsigned int i; float f; } v; v.i = ((unsigned int)u) << 16; return v.f; }
DEVI ushort_t f2bf(float f) {
    union { float f; unsigned int i; } v; v.f = f;
    unsigned int r = v.i + 0x7FFF + ((v.i >> 16) & 1);
    return (ushort_t)(r >> 16);
}

// ---------------- pack: x0c[nl][t][c] (fp32) --------------------------------
__global__ void pack_kernel(const float* __restrict__ ev,
                            const float* __restrict__ tmpl,
                            float* __restrict__ x0, int n0)
{
    const int nl = blockIdx.z;
    const int n  = n0 + nl;
    const int t0 = blockIdx.x * 32;
    const int c0 = blockIdx.y * 32;
    const float* src = (n < 16) ? (ev + n * 65536) : (tmpl + (n - 16) * 65536);
    __shared__ float tile[32][33];
    const int tx = threadIdx.x, ty = threadIdx.y;
#pragma unroll
    for (int k = 0; k < 4; k++) {
        int cl = ty + 8 * k;
        tile[cl][tx] = src[(c0 + cl) * 512 + t0 + tx];
    }
    __syncthreads();
#pragma unroll
    for (int k = 0; k < 4; k++) {
        int tl = ty + 8 * k;
        x0[(nl * 512 + t0 + tl) * 128 + c0 + tx] = tile[tx][tl];
    }
}

// ---------------- weight packs ---------------------------------------------
__global__ void pack_w2(const float* __restrict__ w2, ushort_t* __restrict__ w2p)
{
    for (int idx = blockIdx.x * 256 + threadIdx.x; idx < 15360; idx += gridDim.x * 256) {
        int kh = idx / 3072, rem = idx % 3072;
        int kw = rem / 512;
        int co = (rem >> 4) & 31, ci = rem & 15;
        float v = (kw < 5) ? w2[((co * 16 + ci) * 5 + kh) * 5 + kw] : 0.f;
        w2p[idx] = f2bf(v);
    }
}
__global__ void pack_w3(const float* __restrict__ w3, ushort_t* __restrict__ w3p)
{
    for (int idx = blockIdx.x * 256 + threadIdx.x; idx < 51200; idx += gridDim.x * 256) {
        int kh = idx / 10240, rem = idx % 10240;
        int kw = rem / 2048;
        int co = (rem >> 5) & 63, ci = rem & 31;
        w3p[idx] = f2bf(w3[((co * 32 + ci) * 5 + kh) * 5 + kw]);
    }
}
__global__ void pack_l1w(const float* __restrict__ l1w, ushort_t* __restrict__ l1wp)
{
    for (int idx = blockIdx.x * 256 + threadIdx.x; idx < 262144; idx += gridDim.x * 256) {
        int n = idx >> 12, kp = idx & 4095;
        int r = kp >> 6, j = kp & 63;
        float v = (j < 58) ? l1w[n * 3712 + r * 58 + j] : 0.f;
        l1wp[idx] = f2bf(v);
    }
}

// ---------------- conv1: fp32 direct, CI=1, writes NHWC bf16 ---------------
__global__ void conv1_kernel(const float* __restrict__ in,
                             const float* __restrict__ wgt,
                             const float* __restrict__ bias,
                             ushort_t* __restrict__ out)
{
    const int h0  = blockIdx.x * 4;
    const int w0  = blockIdx.y * 62;
    const int nl  = blockIdx.z;
    const int tid = threadIdx.x;
    const int wl  = tid & 63;
    const int cg  = tid >> 6;

    __shared__ float tin[8 * 68];
    __shared__ float tw[16 * 25];

    float acc[4][4];
#pragma unroll
    for (int j = 0; j < 4; j++)
#pragma unroll
        for (int hh = 0; hh < 4; hh++) acc[j][hh] = 0.f;

    const float* ibase = in + (nl * 512 + h0) * 128 + w0;
    for (int idx = tid; idx < 8 * 66; idx += 256) {
        int r = idx / 66, cc = idx - r * 66;
        tin[r * 68 + cc] = ibase[r * 128 + cc];
    }
    for (int idx = tid; idx < 400; idx += 256) tw[idx] = wgt[idx];
    __syncthreads();
#pragma unroll
    for (int kh = 0; kh < 5; kh++) {
#pragma unroll
        for (int kw = 0; kw < 5; kw++) {
            float iv[4];
#pragma unroll
            for (int hh = 0; hh < 4; hh++)
                iv[hh] = tin[(hh + kh) * 68 + wl + kw];
#pragma unroll
            for (int j = 0; j < 4; j++) {
                float wv = tw[(cg * 4 + j) * 25 + kh * 5 + kw];
#pragma unroll
                for (int hh = 0; hh < 4; hh++)
                    acc[j][hh] = fmaf(wv, iv[hh], acc[j][hh]);
            }
        }
    }
    if (wl < 62) {
#pragma unroll
        for (int hh = 0; hh < 4; hh++) {
            ushort_t pk[4];
#pragma unroll
            for (int j = 0; j < 4; j++)
                pk[j] = f2bf(acc[j][hh] + bias[cg * 4 + j]);
            ushort_t* dst = out + ((size_t)(nl * 508 + h0 + hh) * 124 + w0 + wl) * 16 + cg * 4;
            *(uint2*)dst = *(uint2*)pk;
        }
    }
}

// ---------------- MFMA implicit-GEMM 5x5 conv ------------------------------
// block 256 = 4 waves; wave wv = output row h0+wv; MF m-frags of 16 pixels.
template<int CI, int CO, int NF, int MF, int W_T, int KSTEPS, int KW_TOT,
         int CIP_A, int CIP_B, int H_IN, int W_IN, bool PAD2>
__global__ __launch_bounds__(256, 2) void conv_mfma(
    const ushort_t* __restrict__ in, const ushort_t* __restrict__ wpk,
    const float* __restrict__ bias, ushort_t* __restrict__ out)
{
    constexpr int H_OUT = H_IN - 4;
    constexpr int W_OUT = W_IN - 4;
    constexpr int HALO  = W_T + 6;

    const int h0 = blockIdx.x * 4;
    const int w0 = blockIdx.y * W_T;
    const int nl = blockIdx.z;
    const int tid  = threadIdx.x;
    const int wv   = tid >> 6;
    const int lane = tid & 63;
    const int l16  = lane & 15;
    const int kq   = lane >> 4;

    __shared__ __align__(16) ushort_t As[8 * HALO * CIP_A];
    __shared__ __align__(16) ushort_t Bs[KW_TOT * CO * CIP_B];

    f32x4 acc[MF][NF];
#pragma unroll
    for (int mi = 0; mi < MF; mi++)
#pragma unroll
        for (int ni = 0; ni < NF; ni++) acc[mi][ni] = f32x4{0.f, 0.f, 0.f, 0.f};

    // stage A once: rows h0..h0+7, cols w0..w0+HALO-1, all CI
    constexpr int OCT = CI / 8;
    constexpr int CPR = HALO * OCT;
    for (int idx = tid; idx < 8 * CPR; idx += 256) {
        int r = idx / CPR, rem = idx - r * CPR;
        int c = rem / OCT, oct = rem - c * OCT;
        const ushort_t* src = in + ((size_t)((nl * H_IN + h0 + r) * W_IN + w0 + c)) * CI + oct * 8;
        *(short8*)&As[(r * HALO + c) * CIP_A + oct * 8] = *(const short8*)src;
    }

    const int ciq  = PAD2 ? (kq & 1) * 8 : kq * 8;
    const int kwq  = PAD2 ? (kq >> 1) : 0;

#pragma unroll
    for (int kh = 0; kh < 5; kh++) {
        __syncthreads();
        // stage B for this kh
        for (int idx = tid; idx < KW_TOT * CO * OCT; idx += 256) {
            int kw = idx / (CO * OCT), rem = idx - kw * (CO * OCT);
            int co = rem / OCT, oct = rem - co * OCT;
            const ushort_t* src = wpk + ((size_t)((kh * KW_TOT + kw) * CO + co)) * CI + oct * 8;
            *(short8*)&Bs[(kw * CO + co) * CIP_B + oct * 8] = *(const short8*)src;
        }
        __syncthreads();
#pragma unroll
        for (int st = 0; st < KSTEPS; st++) {
            int colq = (PAD2 ? st * 2 : st) + kwq;
            short8 af[MF], bfv[NF];
#pragma unroll
            for (int mi = 0; mi < MF; mi++)
                af[mi] = *(const short8*)&As[((wv + kh) * HALO + mi * 16 + l16 + colq) * CIP_A + ciq];
#pragma unroll
            for (int ni = 0; ni < NF; ni++)
                bfv[ni] = *(const short8*)&Bs[(colq * CO + ni * 16 + l16) * CIP_B + ciq];
#pragma unroll
            for (int mi = 0; mi < MF; mi++)
#pragma unroll
                for (int ni = 0; ni < NF; ni++)
                    acc[mi][ni] = __builtin_amdgcn_mfma_f32_16x16x32_bf16(
                        af[mi], bfv[ni], acc[mi][ni], 0, 0, 0);
        }
    }

    // epilogue: row m = kq*4+reg (pixel), col n = l16 (co)
    const int h = h0 + wv;
#pragma unroll
    for (int mi = 0; mi < MF; mi++) {
#pragma unroll
        for (int ni = 0; ni < NF; ni++) {
            int co = ni * 16 + l16;
            float bv = bias[co];
#pragma unroll
            for (int reg = 0; reg < 4; reg++) {
                int w = w0 + mi * 16 + kq * 4 + reg;
                if (w < W_OUT)
                    out[((size_t)(nl * H_OUT + h) * W_OUT + w) * CO + co] =
                        f2bf(acc[mi][ni][reg] + bv);
            }
        }
    }
}

// ---------------- pool pass 1: max over (5 rows x 2 cols), NHWC ------------
__global__ void pool_vh(const ushort_t* __restrict__ a3, ushort_t* __restrict__ v2)
{
    const int nl = blockIdx.y;
    const int g  = blockIdx.x * 256 + threadIdx.x;
    if (g >= 3712) return;
    const int j = g >> 6, c = g & 63;
    const ushort_t* base = a3 + (size_t)nl * 500 * 116 * 64;
    float rm[5];
#pragma unroll
    for (int r = 0; r < 4; r++) {
        float a = bf2f(base[((size_t)r * 116 + 2 * j) * 64 + c]);
        float b = bf2f(base[((size_t)r * 116 + 2 * j + 1) * 64 + c]);
        rm[r] = fmaxf(a, b);
    }
    rm[4] = -1e30f;
    int slot = 4;
    for (int s = 0; s < 496; s++) {
        int rr = s + 4;
        float a = bf2f(base[((size_t)rr * 116 + 2 * j) * 64 + c]);
        float b = bf2f(base[((size_t)rr * 116 + 2 * j + 1) * 64 + c]);
        rm[slot] = fmaxf(a, b);
        slot = (slot == 4) ? 0 : slot + 1;
        float m = fmaxf(fmaxf(fmaxf(rm[0], rm[1]), fmaxf(rm[2], rm[3])), rm[4]);
        v2[((size_t)(nl * 496 + s) * 58 + j) * 64 + c] = f2bf(m);
    }
}

// ---------------- pool pass 2: (s,j,c) -> NCHW-flat [c][s][j] --------------
__global__ void pool_tr(const ushort_t* __restrict__ v2, ushort_t* __restrict__ pooled)
{
    const int nl = blockIdx.y;
    const int s0 = blockIdx.x * 2;
    const int t  = threadIdx.x;
    __shared__ ushort_t Li[2 * 58 * 64];
    __shared__ ushort_t Lo[64 * 116];
    const ushort_t* src = v2 + (size_t)(nl * 496 + s0) * 58 * 64;
    for (int i = t; i < 928; i += 256)
        *(short8*)&Li[i * 8] = *(const short8*)&src[i * 8];
    __syncthreads();
    {
        const int c = t & 63, q = t >> 6;     // q: (s = q&1, j-half = q>>1)
        const int s = q & 1, jh = q >> 1;
#pragma unroll
        for (int jj = 0; jj < 29; jj++) {
            int j = jh * 29 + jj;
            Lo[c * 116 + s * 58 + j] = Li[(s * 58 + j) * 64 + c];
        }
    }
    __syncthreads();
    ushort_t* dst = pooled + (size_t)nl * 1841152;
    for (int i = t; i < 7424; i += 256) {
        int c = i / 116, rem = i - c * 116;
        dst[(size_t)c * 28768 + s0 * 58 + rem] = Lo[i];
    }
}

// ---------------- lin1: bf16 MFMA, K'=4096, k-split x4, atomicAdd ----------
__global__ __launch_bounds__(256) void lin1_mfma(
    const ushort_t* __restrict__ pooled, const ushort_t* __restrict__ l1wp,
    float* __restrict__ xb, int n0)
{
    const int mt  = blockIdx.x;       // 31 m-tiles of 16 rows
    const int nl  = blockIdx.y;
    const int kqb = blockIdx.z;       // 4 k-quarters
    const int s0  = mt * 16;
    const int t   = threadIdx.x;
    const int wv  = t >> 6, lane = t & 63, l16 = lane & 15, kq = lane >> 4;

    __shared__ __align__(16) ushort_t As[16 * 40];
    __shared__ __align__(16) ushort_t Bs[64 * 40];

    const ushort_t* pbase = pooled + (size_t)nl * 1841152;
    const int rA = t >> 2, octA = t & 3;          // t<64: A chunk
    const int coB = t >> 2, octB = t & 3;         // all: B chunk

    f32x4 acc = f32x4{0.f, 0.f, 0.f, 0.f};
    const int ks0 = kqb * 32;

    short8 ga, gb;
    {
        int ks = ks0;
        if (t < 64)
            ga = *(const short8*)(pbase + (size_t)(s0 + rA) * 3712 + (ks >> 1) * 58 + (ks & 1) * 32 + octA * 8);
        gb = *(const short8*)(l1wp + (size_t)coB * 4096 + ks * 32 + octB * 8);
    }
    for (int ks = ks0; ks < ks0 + 32; ks++) {
        if (t < 64) *(short8*)&As[rA * 40 + octA * 8] = ga;
        *(short8*)&Bs[coB * 40 + octB * 8] = gb;
        __syncthreads();
        if (ks + 1 < ks0 + 32) {
            int kn = ks + 1;
            if (t < 64)
                ga = *(const short8*)(pbase + (size_t)(s0 + rA) * 3712 + (kn >> 1) * 58 + (kn & 1) * 32 + octA * 8);
            gb = *(const short8*)(l1wp + (size_t)coB * 4096 + kn * 32 + octB * 8);
        }
        short8 af = *(const short8*)&As[l16 * 40 + kq * 8];
        short8 bfv = *(const short8*)&Bs[(wv * 16 + l16) * 40 + kq * 8];
        acc = __builtin_amdgcn_mfma_f32_16x16x32_bf16(af, bfv, acc, 0, 0, 0);
        __syncthreads();
    }
    const int co = wv * 16 + l16;
#pragma unroll
    for (int reg = 0; reg < 4; reg++) {
        int s = s0 + kq * 4 + reg;
        atomicAdd(&xb[((size_t)(n0 + nl) * 496 + s) * 64 + co], acc[reg]);
    }
}

// ---------------- gi = (x + l1b) @ W_ih^T + b_ih ---------------------------
__global__ void gi_kernel(const float* __restrict__ x,
                          const float* __restrict__ Wih,
                          const float* __restrict__ bih,
                          const float* __restrict__ l1b,
                          float* __restrict__ gi)
{
    const int r0 = blockIdx.x * 16;
    const int j  = threadIdx.x; // 192 threads
    __shared__ float xl[16 * 64];
    float w[64];
#pragma unroll
    for (int d = 0; d < 64; d++) w[d] = Wih[j * 64 + d];
    const float bj = bih[j];
    for (int idx = j; idx < 1024; idx += 192)
        xl[idx] = x[r0 * 64 + idx] + l1b[idx & 63];
    __syncthreads();
    for (int s = 0; s < 16; s++) {
        float a = bj;
#pragma unroll
        for (int d = 0; d < 64; d++) a = fmaf(w[d], xl[s * 64 + d], a);
        gi[(size_t)(r0 + s) * 192 + j] = a;
    }
}

// ---------------- chunk-parallel GRU (fp32, unchanged) ---------------------
__global__ __launch_bounds__(64, 1) void gru_kernel(
    const float* __restrict__ gi, const float* __restrict__ Whh,
    const float* __restrict__ bhh, float* __restrict__ Eo,
    float* __restrict__ To)
{
    const int c  = blockIdx.x;
    const int br = c >> 8;
    const int q  = c & 255;
    const int i  = threadIdx.x;
    const float* gb = gi + (size_t)br * 7936 * 192;
    float* out = br ? To : Eo;

    float wr[64], wz[64], wn[64];
#pragma unroll
    for (int k = 0; k < 64; k++) wr[k] = Whh[i * 64 + k];
#pragma unroll
    for (int k = 0; k < 64; k++) wz[k] = Whh[(64 + i) * 64 + k];
#pragma unroll
    for (int k = 0; k < 64; k++) wn[k] = Whh[(128 + i) * 64 + k];
    const float bhr = bhh[i], bhz = bhh[64 + i], bhn = bhh[128 + i];

    __shared__ __align__(16) float hs[64];
    float h[64];
#pragma unroll
    for (int k = 0; k < 64; k++) h[k] = 0.f;
    float hown = 0.f;

    const int cs  = q * 31;
    int start = cs - 96;
    if (start < 0) start = 0;
    const int end = cs + 31;

    float pr[4], pz[4], pn[4];
#pragma unroll
    for (int u = 0; u < 4; u++) {
        int s = start + u;
        if (s < end) {
            const float* g = gb + (size_t)s * 192;
            pr[u] = g[i]; pz[u] = g[64 + i]; pn[u] = g[128 + i];
        } else { pr[u] = 0.f; pz[u] = 0.f; pn[u] = 0.f; }
    }

    int s = start;
    while (s < end) {
#pragma unroll
        for (int u = 0; u < 4; u++) {
            if (s < end) {
                float gr = pr[u], gz = pz[u], gn = pn[u];
                int sp = s + 4;
                if (sp < end) {
                    const float* g = gb + (size_t)sp * 192;
                    pr[u] = g[i]; pz[u] = g[64 + i]; pn[u] = g[128 + i];
                }
                float ar = bhr, az = bhz, an = bhn;
#pragma unroll
                for (int k = 0; k < 64; k++) {
                    ar = fmaf(wr[k], h[k], ar);
                    az = fmaf(wz[k], h[k], az);
                    an = fmaf(wn[k], h[k], an);
                }
                float r  = fsig(gr + ar);
                float z  = fsig(gz + az);
                float nv = ftanh_(gn + r * an);
                float hn = (1.f - z) * nv + z * hown;
                hown = hn;
                hs[i] = hn;
                __syncthreads();
#pragma unroll
                for (int k = 0; k < 16; k++) {
                    float4 v = ((const float4*)hs)[k];
                    h[4 * k + 0] = v.x; h[4 * k + 1] = v.y;
                    h[4 * k + 2] = v.z; h[4 * k + 3] = v.w;
                }
                __syncthreads();
                if (s >= cs) out[(size_t)s * 64 + i] = hn;
                s++;
            }
        }
    }
}

// ---------------- scores[b][m][n] = E[b][m] . Tm[b][n] ----------------------
__global__ void scores_kernel(const float* __restrict__ E,
                              const float* __restrict__ Tm,
                              float* __restrict__ S)
{
    const int b  = blockIdx.z;
    const int m0 = blockIdx.y * 32;
    const int n0 = blockIdx.x * 64;
    const int t  = threadIdx.x;
    const int nl = t & 63, mg = t >> 6;
    __shared__ float El[32 * 64];
    __shared__ float Tms[64 * 65];

    for (int idx = t; idx < 2048; idx += 256) {
        int r = idx >> 6, d = idx & 63;
        int m = m0 + r;
        El[idx] = (m < 496) ? E[((size_t)b * 496 + m) * 64 + d] : 0.f;
    }
    for (int idx = t; idx < 4096; idx += 256) {
        int r = idx >> 6, d = idx & 63;
        int n = n0 + r;
        Tms[d * 65 + r] = (n < 496) ? Tm[((size_t)b * 496 + n) * 64 + d] : 0.f;
    }
    __syncthreads();

    float acc[8];
#pragma unroll
    for (int j = 0; j < 8; j++) acc[j] = 0.f;
#pragma unroll 4
    for (int d = 0; d < 64; d++) {
        float tv = Tms[d * 65 + nl];
#pragma unroll
        for (int j = 0; j < 8; j++)
            acc[j] = fmaf(El[(mg * 8 + j) * 64 + d], tv, acc[j]);
    }
    int n = n0 + nl;
    if (n < 496) {
#pragma unroll
        for (int j = 0; j < 8; j++) {
            int m = m0 + mg * 8 + j;
            if (m < 496) S[((size_t)b * 496 + m) * 496 + n] = acc[j];
        }
    }
}

// ---------------- softmax over m (axis=1), in-place -------------------------
__global__ void colsoftmax_kernel(float* __restrict__ S)
{
    const int b = blockIdx.y;
    const int n = blockIdx.x * 64 + threadIdx.x;
    if (n >= 496) return;
    float* base = S + (size_t)b * 246016 + n;
    float m = -1e30f;
#pragma unroll 4
    for (int mm = 0; mm < 496; mm++) m = fmaxf(m, base[mm * 496]);
    float sum = 0.f;
#pragma unroll 4
    for (int mm = 0; mm < 496; mm++) {
        float e = __expf(base[mm * 496] - m);
        base[mm * 496] = e;
        sum += e;
    }
    float inv = 1.f / sum;
#pragma unroll 4
    for (int mm = 0; mm < 496; mm++) base[mm * 496] *= inv;
}

// ---------------- Tp[b][m][d] = sum_n A[b][m][n] * Tm[b][n][d] --------------
__global__ void tp_kernel(const float* __restrict__ A,
                          const float* __restrict__ Tm,
                          float* __restrict__ Tp)
{
    const int b  = blockIdx.y;
    const int m0 = blockIdx.x * 32;
    const int t  = threadIdx.x;
    const int d  = t & 63, mg = t >> 6;
    __shared__ float As2[32 * 128];
    __shared__ float Ts[128 * 64];
    float acc[8];
#pragma unroll
    for (int j = 0; j < 8; j++) acc[j] = 0.f;

    for (int nc = 0; nc < 512; nc += 128) {
        __syncthreads();
        for (int idx = t; idx < 4096; idx += 256) {
            int r = idx >> 7, cc = idx & 127;
            int m = m0 + r, n = nc + cc;
            As2[idx] = (m < 496 && n < 496)
                          ? A[((size_t)b * 496 + m) * 496 + n] : 0.f;
        }
        for (int idx = t; idx < 8192; idx += 256) {
            int r = idx >> 6, dd = idx & 63;
            int n = nc + r;
            Ts[idx] = (n < 496) ? Tm[((size_t)b * 496 + n) * 64 + dd] : 0.f;
        }
        __syncthreads();
#pragma unroll 4
        for (int nn = 0; nn < 128; nn++) {
            float tv = Ts[nn * 64 + d];
#pragma unroll
            for (int j = 0; j < 8; j++)
                acc[j] = fmaf(As2[(mg * 8 + j) * 128 + nn], tv, acc[j]);
        }
    }
#pragma unroll
    for (int j = 0; j < 8; j++) {
        int m = m0 + mg * 8 + j;
        if (m < 496) Tp[((size_t)b * 496 + m) * 64 + d] = acc[j];
    }
}

// ---------------- att softmax + rep ----------------------------------------
__global__ void attrep_kernel(const float* __restrict__ E,
                              const float* __restrict__ Tp,
                              const float* __restrict__ attw,
                              const float* __restrict__ attb,
                              float* __restrict__ rep)
{
    const int b = blockIdx.x;
    const int t = threadIdx.x; // 256
    __shared__ float aw[64];
    __shared__ float lg[496];
    __shared__ float att[496];
    __shared__ float redm[4], reds[4];
    __shared__ float part[256];

    if (t < 64) aw[t] = attw[t];
    __syncthreads();
    for (int s = t; s < 496; s += 256) {
        const float* Er = E + ((size_t)b * 496 + s) * 64;
        float a = 0.f;
#pragma unroll
        for (int dd = 0; dd < 64; dd++) a = fmaf(Er[dd], aw[dd], a);
        lg[s] = a + attb[0];
    }
    __syncthreads();
    float m = -1e30f;
    for (int s = t; s < 496; s += 256) m = fmaxf(m, lg[s]);
    for (int off = 32; off > 0; off >>= 1)
        m = fmaxf(m, __shfl_xor(m, off, 64));
    if ((t & 63) == 0) redm[t >> 6] = m;
    __syncthreads();
    m = fmaxf(fmaxf(redm[0], redm[1]), fmaxf(redm[2], redm[3]));
    float sum = 0.f;
    for (int s = t; s < 496; s += 256) {
        float e = __expf(lg[s] - m);
        att[s] = e;
        sum += e;
    }
    for (int off = 32; off > 0; off >>= 1) sum += __shfl_xor(sum, off, 64);
    if ((t & 63) == 0) reds[t >> 6] = sum;
    __syncthreads();
    float inv = 1.f / (reds[0] + reds[1] + reds[2] + reds[3]);

    const int d = t & 63, sg = t >> 6;
    float p = 0.f;
    for (int k = 0; k < 124; k++) {
        int s = sg + 4 * k;
        size_t o = ((size_t)b * 496 + s) * 64 + d;
        p = fmaf(att[s] * inv, fabsf(Tp[o] - E[o]), p);
    }
    part[t] = p;
    __syncthreads();
    if (t < 64)
        rep[b * 64 + t] = part[t] + part[64 + t] + part[128 + t] + part[192 + t];
}

// ---------------- tail MLP --------------------------------------------------
__global__ void mlp_kernel(const float* __restrict__ rep,
                           const float* __restrict__ W3,
                           const float* __restrict__ b3,
                           const float* __restrict__ Wc,
                           const float* __restrict__ bc,
                           float* __restrict__ out)
{
    const int b = blockIdx.x;
    const int t = threadIdx.x; // 128
    __shared__ float hr[64];
    __shared__ float h2[128];
    if (t < 64) hr[t] = fmaxf(rep[b * 64 + t], 0.f);
    __syncthreads();
    float a = b3[t];
#pragma unroll
    for (int d = 0; d < 64; d++) a = fmaf(W3[t * 64 + d], hr[d], a);
    h2[t] = fmaxf(a, 0.f);
    __syncthreads();
    if (t < 2) {
        float o = bc[t];
        for (int k = 0; k < 128; k++) o = fmaf(Wc[t * 128 + k], h2[k], o);
        out[b * 2 + t] = o;
    }
}

// ---------------------------------------------------------------------------
extern "C" void kernel_launch(void* const* d_in, const int* in_sizes, int n_in,
                              void* d_out, int out_size, void* d_ws,
                              size_t ws_size, hipStream_t stream)
{
    const float* ev   = (const float*)d_in[0];
    const float* tmpl = (const float*)d_in[1];
    const float* w1   = (const float*)d_in[2];
    const float* b1   = (const float*)d_in[3];
    const float* w2   = (const float*)d_in[4];
    const float* b2   = (const float*)d_in[5];
    const float* w3   = (const float*)d_in[6];
    const float* b3   = (const float*)d_in[7];
    const float* l1w  = (const float*)d_in[8];
    const float* l1b  = (const float*)d_in[9];
    const float* wih  = (const float*)d_in[10];
    const float* whh  = (const float*)d_in[11];
    const float* bih  = (const float*)d_in[12];
    const float* bhh  = (const float*)d_in[13];
    const float* attw = (const float*)d_in[14];
    const float* attb = (const float*)d_in[15];
    const float* l3w  = (const float*)d_in[16];
    const float* l3b  = (const float*)d_in[17];
    const float* clw  = (const float*)d_in[18];
    const float* clb  = (const float*)d_in[19];

    // ---- persistent region (float units) ----
    float* ws = (float*)d_ws;
    float* xb    = ws;                         // 1,015,808
    float* Eb    = xb + 1015808ull;            // 507,904
    float* Tb    = Eb + 507904ull;
    float* Tpb   = Tb + 507904ull;
    float* repb  = Tpb + 507904ull;            // 1,024
    float* w2pf  = repb + 1024ull;             // 7,680 (15,360 bf16)
    float* w3pf  = w2pf + 7680ull;             // 25,600 (51,200 bf16)
    float* l1wpf = w3pf + 25600ull;            // 131,072 (262,144 bf16)
    float* arena = l1wpf + 131072ull;
    const size_t PERSIST = 2704896ull;

    ushort_t* w2p  = (ushort_t*)w2pf;
    ushort_t* w3p  = (ushort_t*)w3pf;
    ushort_t* l1wp = (ushort_t*)l1wpf;

    // ---- chunk size selection ----
    // S1 = C*967,680 f  (x0 fp32 / a2 bf16 / v2 bf16)
    // S2 = C*1,856,000 f (a1 bf16 / a3 bf16 / pooled bf16), guards 2x2048 f
    const int cand[6] = {32, 16, 8, 4, 2, 1};
    int C = 0;
    for (int ci = 0; ci < 6; ci++) {
        size_t a = (size_t)cand[ci] * 2823680ull + 4096ull;
        if (a < 3936256ull) a = 3936256ull;
        if ((PERSIST + a) * sizeof(float) <= ws_size) { C = cand[ci]; break; }
    }
    if (C == 0) return;

    float*    S1 = arena;
    float*    S2 = arena + (size_t)C * 967680ull + 2048ull;
    float*    gib = arena;     // 3,047,424 f (after conv phase)
    float*    Sb  = arena;     // 3,936,256 f (after gru)

    float*    x0  = S1;
    ushort_t* a2  = (ushort_t*)S1;
    ushort_t* v2  = (ushort_t*)S1;
    ushort_t* a1  = (ushort_t*)S2;
    ushort_t* a3  = (ushort_t*)S2;
    ushort_t* pooled = (ushort_t*)S2;

    // ---- weight packs + xb zero ----
    hipMemsetAsync(xb, 0, 1015808ull * sizeof(float), stream);
    pack_w2<<<15, 256, 0, stream>>>(w2, w2p);
    pack_w3<<<50, 256, 0, stream>>>(w3, w3p);
    pack_l1w<<<256, 256, 0, stream>>>(l1w, l1wp);

    // ---- conv trunk + pool + lin1, chunked ----
    for (int n0 = 0; n0 < 32; n0 += C) {
        pack_kernel<<<dim3(16, 4, C), dim3(32, 8), 0, stream>>>(ev, tmpl, x0, n0);
        conv1_kernel<<<dim3(127, 2, C), 256, 0, stream>>>(x0, w1, b1, a1);
        // conv2: CI=16 CO=32 NF=2 MF=4 W_T=64 KSTEPS=3 KW_TOT=6 CIP 24/24
        conv_mfma<16, 32, 2, 4, 64, 3, 6, 24, 24, 508, 124, true>
            <<<dim3(126, 2, C), 256, 0, stream>>>(a1, w2p, b2, a2);
        // conv3: CI=32 CO=64 NF=4 MF=2 W_T=32 KSTEPS=5 KW_TOT=5 CIP 40/40
        conv_mfma<32, 64, 4, 2, 32, 5, 5, 40, 40, 504, 120, false>
            <<<dim3(125, 4, C), 256, 0, stream>>>(a2, w3p, b3, a3);
        pool_vh<<<dim3(15, C), 256, 0, stream>>>(a3, v2);
        pool_tr<<<dim3(248, C), 256, 0, stream>>>(v2, pooled);
        lin1_mfma<<<dim3(31, C, 4), 256, 0, stream>>>(pooled, l1wp, xb, n0);
    }

    // ---- GRU ----
    gi_kernel<<<992, 192, 0, stream>>>(xb, wih, bih, l1b, gib);
    gru_kernel<<<512, 64, 0, stream>>>(gib, whh, bhh, Eb, Tb);

    // ---- alignment ----
    scores_kernel<<<dim3(8, 16, 16), 256, 0, stream>>>(Eb, Tb, Sb);
    colsoftmax_kernel<<<dim3(8, 16), 64, 0, stream>>>(Sb);
    tp_kernel<<<dim3(16, 16), 256, 0, stream>>>(Sb, Tb, Tpb);

    // ---- attention + tail ----
    attrep_kernel<<<16, 256, 0, stream>>>(Eb, Tpb, attw, attb, repb);
    mlp_kernel<<<16, 128, 0, stream>>>(repb, l3w, l3b, clw, clb,
                                       (float*)d_out);
}

// Round 5
// 1157.688 us; speedup vs baseline: 16.0265x; 1.1529x over previous
//
#include <hip/hip_runtime.h>
#include <hip/hip_bf16.h>
#include <math.h>

// ---------------------------------------------------------------------------
// DeepTemplateMatchingModule — round 5.
// Round-4 bug: materialized "k-padded pooled" assumed reshape row s =
// {pooled[c][s][:]}, but the raw (64,496,58)->(496,3712) reshape gives row s
// = t-rows t=64s..64s+63 with t=c'*496+s' (channel-crossing). Fix: keep the
// NCHW-flat pooled buffer (round-3 layout, provably correct) and stage lin1's
// A-tile straight from it: padded k-block kb -> addr row*3712 + (k0>>6)*58 +
// oct*8 (j>=58 garbage x zero B-weight). All round-4 conv/pool improvements
// (conflict-free LDS planes, occupancy 4, pool_vh s-chunks) retained.
// ---------------------------------------------------------------------------

#define DEVI static __device__ __forceinline__
typedef __attribute__((ext_vector_type(8))) short short8;
typedef __attribute__((ext_vector_type(4))) float f32x4;
typedef unsigned short ushort_t;

DEVI float fsig(float x)   { return 1.f / (1.f + __expf(-x)); }
DEVI float ftanh_(float x) { return 2.f / (1.f + __expf(-2.f * x)) - 1.f; }
DEVI float bf2f(ushort_t u) { union { unsigned int i; float f; } v; v.i = ((unsigned int)u) << 16; return v.f; }
DEVI ushort_t f2bf(float f) {
    union { float f; unsigned int i; } v; v.f = f;
    unsigned int r = v.i + 0x7FFF + ((v.i >> 16) & 1);
    return (ushort_t)(r >> 16);
}

// ---------------- pack: x0c[nl][t][c] (fp32) --------------------------------
__global__ void pack_kernel(const float* __restrict__ ev,
                            const float* __restrict__ tmpl,
                            float* __restrict__ x0, int n0)
{
    const int nl = blockIdx.z;
    const int n  = n0 + nl;
    const int t0 = blockIdx.x * 32;
    const int c0 = blockIdx.y * 32;
    const float* src = (n < 16) ? (ev + n * 65536) : (tmpl + (n - 16) * 65536);
    __shared__ float tile[32][33];
    const int tx = threadIdx.x, ty = threadIdx.y;
#pragma unroll
    for (int k = 0; k < 4; k++) {
        int cl = ty + 8 * k;
        tile[cl][tx] = src[(c0 + cl) * 512 + t0 + tx];
    }
    __syncthreads();
#pragma unroll
    for (int k = 0; k < 4; k++) {
        int tl = ty + 8 * k;
        x0[(nl * 512 + t0 + tl) * 128 + c0 + tx] = tile[tx][tl];
    }
}

// ---------------- weight packs ---------------------------------------------
__global__ void pack_w2(const float* __restrict__ w2, ushort_t* __restrict__ w2p)
{
    for (int idx = blockIdx.x * 256 + threadIdx.x; idx < 15360; idx += gridDim.x * 256) {
        int kh = idx / 3072, rem = idx % 3072;
        int kw = rem / 512;
        int co = (rem >> 4) & 31, ci = rem & 15;
        float v = (kw < 5) ? w2[((co * 16 + ci) * 5 + kh) * 5 + kw] : 0.f;
        w2p[idx] = f2bf(v);
    }
}
__global__ void pack_w3(const float* __restrict__ w3, ushort_t* __restrict__ w3p)
{
    for (int idx = blockIdx.x * 256 + threadIdx.x; idx < 51200; idx += gridDim.x * 256) {
        int kh = idx / 10240, rem = idx % 10240;
        int kw = rem / 2048;
        int co = (rem >> 5) & 63, ci = rem & 31;
        w3p[idx] = f2bf(w3[((co * 32 + ci) * 5 + kh) * 5 + kw]);
    }
}
__global__ void pack_l1w(const float* __restrict__ l1w, ushort_t* __restrict__ l1wp)
{
    for (int idx = blockIdx.x * 256 + threadIdx.x; idx < 262144; idx += gridDim.x * 256) {
        int n = idx >> 12, kp = idx & 4095;
        int r = kp >> 6, j = kp & 63;
        float v = (j < 58) ? l1w[n * 3712 + r * 58 + j] : 0.f;
        l1wp[idx] = f2bf(v);
    }
}

// ---------------- conv1: fp32 direct, CI=1, writes NHWC bf16 ---------------
__global__ void conv1_kernel(const float* __restrict__ in,
                             const float* __restrict__ wgt,
                             const float* __restrict__ bias,
                             ushort_t* __restrict__ out)
{
    const int h0  = blockIdx.x * 4;
    const int w0  = blockIdx.y * 62;
    const int nl  = blockIdx.z;
    const int tid = threadIdx.x;
    const int wl  = tid & 63;
    const int cg  = tid >> 6;

    __shared__ float tin[8 * 68];
    __shared__ float tw[16 * 25];

    float acc[4][4];
#pragma unroll
    for (int j = 0; j < 4; j++)
#pragma unroll
        for (int hh = 0; hh < 4; hh++) acc[j][hh] = 0.f;

    const float* ibase = in + (nl * 512 + h0) * 128 + w0;
    for (int idx = tid; idx < 8 * 66; idx += 256) {
        int r = idx / 66, cc = idx - r * 66;
        tin[r * 68 + cc] = ibase[r * 128 + cc];
    }
    for (int idx = tid; idx < 400; idx += 256) tw[idx] = wgt[idx];
    __syncthreads();
#pragma unroll
    for (int kh = 0; kh < 5; kh++) {
#pragma unroll
        for (int kw = 0; kw < 5; kw++) {
            float iv[4];
#pragma unroll
            for (int hh = 0; hh < 4; hh++)
                iv[hh] = tin[(hh + kh) * 68 + wl + kw];
#pragma unroll
            for (int j = 0; j < 4; j++) {
                float wv = tw[(cg * 4 + j) * 25 + kh * 5 + kw];
#pragma unroll
                for (int hh = 0; hh < 4; hh++)
                    acc[j][hh] = fmaf(wv, iv[hh], acc[j][hh]);
            }
        }
    }
    if (wl < 62) {
#pragma unroll
        for (int hh = 0; hh < 4; hh++) {
            ushort_t pk[4];
#pragma unroll
            for (int j = 0; j < 4; j++)
                pk[j] = f2bf(acc[j][hh] + bias[cg * 4 + j]);
            ushort_t* dst = out + ((size_t)(nl * 508 + h0 + hh) * 124 + w0 + wl) * 16 + cg * 4;
            *(uint2*)dst = *(uint2*)pk;
        }
    }
}

// ---------------- MFMA implicit-GEMM 5x5 conv (conflict-free LDS) ----------
template<int CI, int CO, int NF, int MF, int W_T, int KSTEPS, int KW_TOT,
         int H_IN, int W_IN, bool PAD2>
__global__ __launch_bounds__(256, 4) void conv_mfma(
    const ushort_t* __restrict__ in, const ushort_t* __restrict__ wpk,
    const float* __restrict__ bias, ushort_t* __restrict__ out)
{
    constexpr int H_OUT = H_IN - 4;
    constexpr int W_OUT = W_IN - 4;
    constexpr int HALO  = W_T + 6;
    constexpr int OCT   = CI / 8;
    constexpr int APL   = 8 * HALO;
    constexpr int BPL   = KW_TOT * CO;

    const int h0 = blockIdx.x * 4;
    const int w0 = blockIdx.y * W_T;
    const int nl = blockIdx.z;
    const int tid  = threadIdx.x;
    const int wv   = tid >> 6;
    const int lane = tid & 63;
    const int l16  = lane & 15;
    const int kq   = lane >> 4;

    __shared__ __align__(16) ushort_t As[OCT * APL * 8];
    __shared__ __align__(16) ushort_t Bs[OCT * BPL * 8];

    f32x4 acc[MF][NF];
#pragma unroll
    for (int mi = 0; mi < MF; mi++)
#pragma unroll
        for (int ni = 0; ni < NF; ni++) acc[mi][ni] = f32x4{0.f, 0.f, 0.f, 0.f};

    for (int idx = tid; idx < OCT * APL; idx += 256) {
        int oct = idx / APL, e = idx - oct * APL;
        int r = e / HALO, c = e - r * HALO;
        const ushort_t* src = in + ((size_t)((nl * H_IN + h0 + r) * W_IN + w0 + c)) * CI + oct * 8;
        *(short8*)&As[idx * 8] = *(const short8*)src;
    }

    const int aoct = PAD2 ? (kq & 1) : kq;
    const int kwq  = PAD2 ? (kq >> 1) : 0;

#pragma unroll
    for (int kh = 0; kh < 5; kh++) {
        __syncthreads();
        for (int idx = tid; idx < OCT * BPL; idx += 256) {
            int oct = idx / BPL, e = idx - oct * BPL;
            int kw = e / CO, co = e - kw * CO;
            const ushort_t* src = wpk + ((size_t)((kh * KW_TOT + kw) * CO + co)) * CI + oct * 8;
            *(short8*)&Bs[idx * 8] = *(const short8*)src;
        }
        __syncthreads();
#pragma unroll
        for (int st = 0; st < KSTEPS; st++) {
            int colq = (PAD2 ? st * 2 : st) + kwq;
            short8 af[MF], bfv[NF];
#pragma unroll
            for (int mi = 0; mi < MF; mi++)
                af[mi] = *(const short8*)&As[(aoct * APL + (wv + kh) * HALO + mi * 16 + l16 + colq) * 8];
#pragma unroll
            for (int ni = 0; ni < NF; ni++)
                bfv[ni] = *(const short8*)&Bs[(aoct * BPL + colq * CO + ni * 16 + l16) * 8];
#pragma unroll
            for (int mi = 0; mi < MF; mi++)
#pragma unroll
                for (int ni = 0; ni < NF; ni++)
                    acc[mi][ni] = __builtin_amdgcn_mfma_f32_16x16x32_bf16(
                        af[mi], bfv[ni], acc[mi][ni], 0, 0, 0);
        }
    }

    const int h = h0 + wv;
#pragma unroll
    for (int mi = 0; mi < MF; mi++) {
#pragma unroll
        for (int ni = 0; ni < NF; ni++) {
            int co = ni * 16 + l16;
            float bv = bias[co];
#pragma unroll
            for (int reg = 0; reg < 4; reg++) {
                int w = w0 + mi * 16 + kq * 4 + reg;
                if (w < W_OUT)
                    out[((size_t)(nl * H_OUT + h) * W_OUT + w) * CO + co] =
                        f2bf(acc[mi][ni][reg] + bv);
            }
        }
    }
}

// ---------------- pool pass 1: max over (5 rows x 2 cols), 8 s-chunks ------
__global__ void pool_vh(const ushort_t* __restrict__ a3, ushort_t* __restrict__ v2)
{
    const int nl = blockIdx.z;
    const int sc = blockIdx.y;           // 8 chunks of 62
    const int g  = blockIdx.x * 256 + threadIdx.x;
    if (g >= 3712) return;
    const int j = g >> 6, c = g & 63;
    const ushort_t* base = a3 + (size_t)nl * 500 * 116 * 64 + (size_t)(2 * j) * 64 + c;
    const int s0 = sc * 62;
    float rm[5];
#pragma unroll
    for (int r = 0; r < 4; r++) {
        float a = bf2f(base[(size_t)(s0 + r) * 7424]);
        float b = bf2f(base[(size_t)(s0 + r) * 7424 + 64]);
        rm[r] = fmaxf(a, b);
    }
    rm[4] = -1e30f;
    int slot = 4;
    for (int s = s0; s < s0 + 62; s++) {
        int rr = s + 4;
        float a = bf2f(base[(size_t)rr * 7424]);
        float b = bf2f(base[(size_t)rr * 7424 + 64]);
        rm[slot] = fmaxf(a, b);
        slot = (slot == 4) ? 0 : slot + 1;
        float m = fmaxf(fmaxf(fmaxf(rm[0], rm[1]), fmaxf(rm[2], rm[3])), rm[4]);
        v2[((size_t)(nl * 496 + s) * 58 + j) * 64 + c] = f2bf(m);
    }
}

// ---------------- pool pass 2: (s,j,c) -> NCHW-flat pooled[c][s][j] --------
__global__ void pool_tr(const ushort_t* __restrict__ v2, ushort_t* __restrict__ pooled)
{
    const int nl = blockIdx.y;
    const int s0 = blockIdx.x * 2;
    const int t  = threadIdx.x;
    __shared__ ushort_t Li[2 * 58 * 64];
    __shared__ ushort_t Lo[64 * 116];
    const ushort_t* src = v2 + (size_t)(nl * 496 + s0) * 58 * 64;
    for (int i = t; i < 928; i += 256)
        *(short8*)&Li[i * 8] = *(const short8*)&src[i * 8];
    __syncthreads();
    {
        const int c = t & 63, q = t >> 6;
        const int s = q & 1, jh = q >> 1;
#pragma unroll
        for (int jj = 0; jj < 29; jj++) {
            int j = jh * 29 + jj;
            Lo[c * 116 + s * 58 + j] = Li[(s * 58 + j) * 64 + c];
        }
    }
    __syncthreads();
    ushort_t* dst = pooled + (size_t)nl * 1841152;
    for (int i = t; i < 7424; i += 256) {
        int c = i / 116, rem = i - c * 116;
        dst[(size_t)c * 28768 + s0 * 58 + rem] = Lo[i];
    }
}

// ---------------- lin1: M=64 N=64 K=1024/block MFMA, k-split x4 ------------
// A staged straight from NCHW-flat pooled: padded block kb -> t-row r=k0>>6,
// addr = row*3712 + r*58 + oct*8 (j>=58 garbage x zero B weight).
__global__ __launch_bounds__(256) void lin1_mfma(
    const ushort_t* __restrict__ pooled, const ushort_t* __restrict__ l1wp,
    float* __restrict__ xb, int n0, int RT)
{
    const int mt  = blockIdx.x;
    const int kqb = blockIdx.y;          // 4 k-quarters
    const int r0  = mt * 64;
    const int t   = threadIdx.x;
    const int wv  = t >> 6, lane = t & 63, l16 = lane & 15, kq = lane >> 4;

    __shared__ __align__(16) ushort_t As[8 * 64 * 8];  // [oct][row]
    __shared__ __align__(16) ushort_t Bs[8 * 64 * 8];  // [oct][co]

    f32x4 acc[4];
#pragma unroll
    for (int ni = 0; ni < 4; ni++) acc[ni] = f32x4{0.f, 0.f, 0.f, 0.f};

    for (int kb = 0; kb < 16; kb++) {
        const int k0 = kqb * 1024 + kb * 64;
        const int r  = k0 >> 6;          // t-row within each reshape row
        __syncthreads();
        for (int idx = t; idx < 512; idx += 256) {
            int oct = idx >> 6, row = idx & 63;
            int rr = r0 + row;
            short8 v = short8{0, 0, 0, 0, 0, 0, 0, 0};
            if (rr < RT)
                v = *(const short8*)(pooled + (size_t)rr * 3712 + r * 58 + oct * 8);
            *(short8*)&As[idx * 8] = v;
        }
        for (int idx = t; idx < 512; idx += 256) {
            int oct = idx >> 6, co = idx & 63;
            *(short8*)&Bs[idx * 8] =
                *(const short8*)(l1wp + (size_t)co * 4096 + k0 + oct * 8);
        }
        __syncthreads();
#pragma unroll
        for (int st = 0; st < 2; st++) {
            short8 af = *(const short8*)&As[((st * 4 + kq) * 64 + wv * 16 + l16) * 8];
#pragma unroll
            for (int ni = 0; ni < 4; ni++) {
                short8 bfv = *(const short8*)&Bs[((st * 4 + kq) * 64 + ni * 16 + l16) * 8];
                acc[ni] = __builtin_amdgcn_mfma_f32_16x16x32_bf16(af, bfv, acc[ni], 0, 0, 0);
            }
        }
    }
#pragma unroll
    for (int ni = 0; ni < 4; ni++) {
        int co = ni * 16 + l16;
#pragma unroll
        for (int reg = 0; reg < 4; reg++) {
            int rr = r0 + wv * 16 + kq * 4 + reg;
            if (rr < RT)
                atomicAdd(&xb[((size_t)n0 * 496 + rr) * 64 + co], acc[ni][reg]);
        }
    }
}

// ---------------- gi = (x + l1b) @ W_ih^T + b_ih ---------------------------
__global__ void gi_kernel(const float* __restrict__ x,
                          const float* __restrict__ Wih,
                          const float* __restrict__ bih,
                          const float* __restrict__ l1b,
                          float* __restrict__ gi)
{
    const int r0 = blockIdx.x * 16;
    const int j  = threadIdx.x; // 192 threads
    __shared__ float xl[16 * 64];
    float w[64];
#pragma unroll
    for (int d = 0; d < 64; d++) w[d] = Wih[j * 64 + d];
    const float bj = bih[j];
    for (int idx = j; idx < 1024; idx += 192)
        xl[idx] = x[r0 * 64 + idx] + l1b[idx & 63];
    __syncthreads();
    for (int s = 0; s < 16; s++) {
        float a = bj;
#pragma unroll
        for (int d = 0; d < 64; d++) a = fmaf(w[d], xl[s * 64 + d], a);
        gi[(size_t)(r0 + s) * 192 + j] = a;
    }
}

// ---------------- chunk-parallel GRU (fp32, unchanged) ---------------------
__global__ __launch_bounds__(64, 1) void gru_kernel(
    const float* __restrict__ gi, const float* __restrict__ Whh,
    const float* __restrict__ bhh, float* __restrict__ Eo,
    float* __restrict__ To)
{
    const int c  = blockIdx.x;
    const int br = c >> 8;
    const int q  = c & 255;
    const int i  = threadIdx.x;
    const float* gb = gi + (size_t)br * 7936 * 192;
    float* out = br ? To : Eo;

    float wr[64], wz[64], wn[64];
#pragma unroll
    for (int k = 0; k < 64; k++) wr[k] = Whh[i * 64 + k];
#pragma unroll
    for (int k = 0; k < 64; k++) wz[k] = Whh[(64 + i) * 64 + k];
#pragma unroll
    for (int k = 0; k < 64; k++) wn[k] = Whh[(128 + i) * 64 + k];
    const float bhr = bhh[i], bhz = bhh[64 + i], bhn = bhh[128 + i];

    __shared__ __align__(16) float hs[64];
    float h[64];
#pragma unroll
    for (int k = 0; k < 64; k++) h[k] = 0.f;
    float hown = 0.f;

    const int cs  = q * 31;
    int start = cs - 96;
    if (start < 0) start = 0;
    const int end = cs + 31;

    float pr[4], pz[4], pn[4];
#pragma unroll
    for (int u = 0; u < 4; u++) {
        int s = start + u;
        if (s < end) {
            const float* g = gb + (size_t)s * 192;
            pr[u] = g[i]; pz[u] = g[64 + i]; pn[u] = g[128 + i];
        } else { pr[u] = 0.f; pz[u] = 0.f; pn[u] = 0.f; }
    }

    int s = start;
    while (s < end) {
#pragma unroll
        for (int u = 0; u < 4; u++) {
            if (s < end) {
                float gr = pr[u], gz = pz[u], gn = pn[u];
                int sp = s + 4;
                if (sp < end) {
                    const float* g = gb + (size_t)sp * 192;
                    pr[u] = g[i]; pz[u] = g[64 + i]; pn[u] = g[128 + i];
                }
                float ar = bhr, az = bhz, an = bhn;
#pragma unroll
                for (int k = 0; k < 64; k++) {
                    ar = fmaf(wr[k], h[k], ar);
                    az = fmaf(wz[k], h[k], az);
                    an = fmaf(wn[k], h[k], an);
                }
                float r  = fsig(gr + ar);
                float z  = fsig(gz + az);
                float nv = ftanh_(gn + r * an);
                float hn = (1.f - z) * nv + z * hown;
                hown = hn;
                hs[i] = hn;
                __syncthreads();
#pragma unroll
                for (int k = 0; k < 16; k++) {
                    float4 v = ((const float4*)hs)[k];
                    h[4 * k + 0] = v.x; h[4 * k + 1] = v.y;
                    h[4 * k + 2] = v.z; h[4 * k + 3] = v.w;
                }
                __syncthreads();
                if (s >= cs) out[(size_t)s * 64 + i] = hn;
                s++;
            }
        }
    }
}

// ---------------- scores[b][m][n] = E[b][m] . Tm[b][n] ----------------------
__global__ void scores_kernel(const float* __restrict__ E,
                              const float* __restrict__ Tm,
                              float* __restrict__ S)
{
    const int b  = blockIdx.z;
    const int m0 = blockIdx.y * 32;
    const int n0 = blockIdx.x * 64;
    const int t  = threadIdx.x;
    const int nl = t & 63, mg = t >> 6;
    __shared__ float El[32 * 64];
    __shared__ float Tms[64 * 65];

    for (int idx = t; idx < 2048; idx += 256) {
        int r = idx >> 6, d = idx & 63;
        int m = m0 + r;
        El[idx] = (m < 496) ? E[((size_t)b * 496 + m) * 64 + d] : 0.f;
    }
    for (int idx = t; idx < 4096; idx += 256) {
        int r = idx >> 6, d = idx & 63;
        int n = n0 + r;
        Tms[d * 65 + r] = (n < 496) ? Tm[((size_t)b * 496 + n) * 64 + d] : 0.f;
    }
    __syncthreads();

    float acc[8];
#pragma unroll
    for (int j = 0; j < 8; j++) acc[j] = 0.f;
#pragma unroll 4
    for (int d = 0; d < 64; d++) {
        float tv = Tms[d * 65 + nl];
#pragma unroll
        for (int j = 0; j < 8; j++)
            acc[j] = fmaf(El[(mg * 8 + j) * 64 + d], tv, acc[j]);
    }
    int n = n0 + nl;
    if (n < 496) {
#pragma unroll
        for (int j = 0; j < 8; j++) {
            int m = m0 + mg * 8 + j;
            if (m < 496) S[((size_t)b * 496 + m) * 496 + n] = acc[j];
        }
    }
}

// ---------------- softmax over m (axis=1), in-place -------------------------
__global__ void colsoftmax_kernel(float* __restrict__ S)
{
    const int b = blockIdx.y;
    const int n = blockIdx.x * 64 + threadIdx.x;
    if (n >= 496) return;
    float* base = S + (size_t)b * 246016 + n;
    float m = -1e30f;
#pragma unroll 4
    for (int mm = 0; mm < 496; mm++) m = fmaxf(m, base[mm * 496]);
    float sum = 0.f;
#pragma unroll 4
    for (int mm = 0; mm < 496; mm++) {
        float e = __expf(base[mm * 496] - m);
        base[mm * 496] = e;
        sum += e;
    }
    float inv = 1.f / sum;
#pragma unroll 4
    for (int mm = 0; mm < 496; mm++) base[mm * 496] *= inv;
}

// ---------------- Tp[b][m][d] = sum_n A[b][m][n] * Tm[b][n][d] --------------
__global__ void tp_kernel(const float* __restrict__ A,
                          const float* __restrict__ Tm,
                          float* __restrict__ Tp)
{
    const int b  = blockIdx.y;
    const int m0 = blockIdx.x * 32;
    const int t  = threadIdx.x;
    const int d  = t & 63, mg = t >> 6;
    __shared__ float As2[32 * 128];
    __shared__ float Ts[128 * 64];
    float acc[8];
#pragma unroll
    for (int j = 0; j < 8; j++) acc[j] = 0.f;

    for (int nc = 0; nc < 512; nc += 128) {
        __syncthreads();
        for (int idx = t; idx < 4096; idx += 256) {
            int r = idx >> 7, cc = idx & 127;
            int m = m0 + r, n = nc + cc;
            As2[idx] = (m < 496 && n < 496)
                          ? A[((size_t)b * 496 + m) * 496 + n] : 0.f;
        }
        for (int idx = t; idx < 8192; idx += 256) {
            int r = idx >> 6, dd = idx & 63;
            int n = nc + r;
            Ts[idx] = (n < 496) ? Tm[((size_t)b * 496 + n) * 64 + dd] : 0.f;
        }
        __syncthreads();
#pragma unroll 4
        for (int nn = 0; nn < 128; nn++) {
            float tv = Ts[nn * 64 + d];
#pragma unroll
            for (int j = 0; j < 8; j++)
                acc[j] = fmaf(As2[(mg * 8 + j) * 128 + nn], tv, acc[j]);
        }
    }
#pragma unroll
    for (int j = 0; j < 8; j++) {
        int m = m0 + mg * 8 + j;
        if (m < 496) Tp[((size_t)b * 496 + m) * 64 + d] = acc[j];
    }
}

// ---------------- att softmax + rep ----------------------------------------
__global__ void attrep_kernel(const float* __restrict__ E,
                              const float* __restrict__ Tp,
                              const float* __restrict__ attw,
                              const float* __restrict__ attb,
                              float* __restrict__ rep)
{
    const int b = blockIdx.x;
    const int t = threadIdx.x; // 256
    __shared__ float aw[64];
    __shared__ float lg[496];
    __shared__ float att[496];
    __shared__ float redm[4], reds[4];
    __shared__ float part[256];

    if (t < 64) aw[t] = attw[t];
    __syncthreads();
    for (int s = t; s < 496; s += 256) {
        const float* Er = E + ((size_t)b * 496 + s) * 64;
        float a = 0.f;
#pragma unroll
        for (int dd = 0; dd < 64; dd++) a = fmaf(Er[dd], aw[dd], a);
        lg[s] = a + attb[0];
    }
    __syncthreads();
    float m = -1e30f;
    for (int s = t; s < 496; s += 256) m = fmaxf(m, lg[s]);
    for (int off = 32; off > 0; off >>= 1)
        m = fmaxf(m, __shfl_xor(m, off, 64));
    if ((t & 63) == 0) redm[t >> 6] = m;
    __syncthreads();
    m = fmaxf(fmaxf(redm[0], redm[1]), fmaxf(redm[2], redm[3]));
    float sum = 0.f;
    for (int s = t; s < 496; s += 256) {
        float e = __expf(lg[s] - m);
        att[s] = e;
        sum += e;
    }
    for (int off = 32; off > 0; off >>= 1) sum += __shfl_xor(sum, off, 64);
    if ((t & 63) == 0) reds[t >> 6] = sum;
    __syncthreads();
    float inv = 1.f / (reds[0] + reds[1] + reds[2] + reds[3]);

    const int d = t & 63, sg = t >> 6;
    float p = 0.f;
    for (int k = 0; k < 124; k++) {
        int s = sg + 4 * k;
        size_t o = ((size_t)b * 496 + s) * 64 + d;
        p = fmaf(att[s] * inv, fabsf(Tp[o] - E[o]), p);
    }
    part[t] = p;
    __syncthreads();
    if (t < 64)
        rep[b * 64 + t] = part[t] + part[64 + t] + part[128 + t] + part[192 + t];
}

// ---------------- tail MLP --------------------------------------------------
__global__ void mlp_kernel(const float* __restrict__ rep,
                           const float* __restrict__ W3,
                           const float* __restrict__ b3,
                           const float* __restrict__ Wc,
                           const float* __restrict__ bc,
                           float* __restrict__ out)
{
    const int b = blockIdx.x;
    const int t = threadIdx.x; // 128
    __shared__ float hr[64];
    __shared__ float h2[128];
    if (t < 64) hr[t] = fmaxf(rep[b * 64 + t], 0.f);
    __syncthreads();
    float a = b3[t];
#pragma unroll
    for (int d = 0; d < 64; d++) a = fmaf(W3[t * 64 + d], hr[d], a);
    h2[t] = fmaxf(a, 0.f);
    __syncthreads();
    if (t < 2) {
        float o = bc[t];
        for (int k = 0; k < 128; k++) o = fmaf(Wc[t * 128 + k], h2[k], o);
        out[b * 2 + t] = o;
    }
}

// ---------------------------------------------------------------------------
extern "C" void kernel_launch(void* const* d_in, const int* in_sizes, int n_in,
                              void* d_out, int out_size, void* d_ws,
                              size_t ws_size, hipStream_t stream)
{
    const float* ev   = (const float*)d_in[0];
    const float* tmpl = (const float*)d_in[1];
    const float* w1   = (const float*)d_in[2];
    const float* b1   = (const float*)d_in[3];
    const float* w2   = (const float*)d_in[4];
    const float* b2   = (const float*)d_in[5];
    const float* w3   = (const float*)d_in[6];
    const float* b3   = (const float*)d_in[7];
    const float* l1w  = (const float*)d_in[8];
    const float* l1b  = (const float*)d_in[9];
    const float* wih  = (const float*)d_in[10];
    const float* whh  = (const float*)d_in[11];
    const float* bih  = (const float*)d_in[12];
    const float* bhh  = (const float*)d_in[13];
    const float* attw = (const float*)d_in[14];
    const float* attb = (const float*)d_in[15];
    const float* l3w  = (const float*)d_in[16];
    const float* l3b  = (const float*)d_in[17];
    const float* clw  = (const float*)d_in[18];
    const float* clb  = (const float*)d_in[19];

    // ---- persistent region (float units) ----
    float* ws = (float*)d_ws;
    float* xb    = ws;                         // 1,015,808
    float* Eb    = xb + 1015808ull;            // 507,904
    float* Tb    = Eb + 507904ull;
    float* Tpb   = Tb + 507904ull;
    float* repb  = Tpb + 507904ull;            // 1,024
    float* w2pf  = repb + 1024ull;             // 7,680 (15,360 bf16)
    float* w3pf  = w2pf + 7680ull;             // 25,600 (51,200 bf16)
    float* l1wpf = w3pf + 25600ull;            // 131,072 (262,144 bf16)
    float* arena = l1wpf + 131072ull;
    const size_t PERSIST = 2704896ull;

    ushort_t* w2p  = (ushort_t*)w2pf;
    ushort_t* w3p  = (ushort_t*)w3pf;
    ushort_t* l1wp = (ushort_t*)l1wpf;

    // ---- chunk size selection ----
    const int cand[6] = {32, 16, 8, 4, 2, 1};
    int C = 0;
    for (int ci = 0; ci < 6; ci++) {
        size_t a = (size_t)cand[ci] * 2823680ull + 4096ull;
        if (a < 3936256ull) a = 3936256ull;
        if ((PERSIST + a) * sizeof(float) <= ws_size) { C = cand[ci]; break; }
    }
    if (C == 0) return;

    float*    S1 = arena;
    float*    S2 = arena + (size_t)C * 967680ull + 2048ull;
    float*    gib = arena;     // 3,047,424 f (after conv phase)
    float*    Sb  = arena;     // 3,936,256 f (after gru)

    float*    x0  = S1;
    ushort_t* a2  = (ushort_t*)S1;
    ushort_t* v2  = (ushort_t*)S1;
    ushort_t* a1  = (ushort_t*)S2;
    ushort_t* a3  = (ushort_t*)S2;
    ushort_t* pooled = (ushort_t*)S2;  // NCHW-flat: C x (64*496*58)

    // ---- weight packs + xb zero ----
    hipMemsetAsync(xb, 0, 1015808ull * sizeof(float), stream);
    pack_w2<<<15, 256, 0, stream>>>(w2, w2p);
    pack_w3<<<50, 256, 0, stream>>>(w3, w3p);
    pack_l1w<<<256, 256, 0, stream>>>(l1w, l1wp);

    const int RT = C * 496;
    const int mtiles = (RT + 63) / 64;

    // ---- conv trunk + pool + lin1, chunked ----
    for (int n0 = 0; n0 < 32; n0 += C) {
        pack_kernel<<<dim3(16, 4, C), dim3(32, 8), 0, stream>>>(ev, tmpl, x0, n0);
        conv1_kernel<<<dim3(127, 2, C), 256, 0, stream>>>(x0, w1, b1, a1);
        conv_mfma<16, 32, 2, 4, 64, 3, 6, 508, 124, true>
            <<<dim3(126, 2, C), 256, 0, stream>>>(a1, w2p, b2, a2);
        conv_mfma<32, 64, 4, 2, 32, 5, 5, 504, 120, false>
            <<<dim3(125, 4, C), 256, 0, stream>>>(a2, w3p, b3, a3);
        pool_vh<<<dim3(15, 8, C), 256, 0, stream>>>(a3, v2);
        pool_tr<<<dim3(248, C), 256, 0, stream>>>(v2, pooled);
        lin1_mfma<<<dim3(mtiles, 4), 256, 0, stream>>>(pooled, l1wp, xb, n0, RT);
    }

    // ---- GRU ----
    gi_kernel<<<992, 192, 0, stream>>>(xb, wih, bih, l1b, gib);
    gru_kernel<<<512, 64, 0, stream>>>(gib, whh, bhh, Eb, Tb);

    // ---- alignment ----
    scores_kernel<<<dim3(8, 16, 16), 256, 0, stream>>>(Eb, Tb, Sb);
    colsoftmax_kernel<<<dim3(8, 16), 64, 0, stream>>>(Sb);
    tp_kernel<<<dim3(16, 16), 256, 0, stream>>>(Sb, Tb, Tpb);

    // ---- attention + tail ----
    attrep_kernel<<<16, 256, 0, stream>>>(Eb, Tpb, attw, attb, repb);
    mlp_kernel<<<16, 128, 0, stream>>>(repb, l3w, l3b, clw, clb,
                                       (float*)d_out);
}

// Round 6
// 991.802 us; speedup vs baseline: 18.7071x; 1.1673x over previous
//
#include <hip/hip_runtime.h>
#include <hip/hip_bf16.h>
#include <math.h>

// ---------------------------------------------------------------------------
// DeepTemplateMatchingModule — round 6.
// vs round 5: colsoftmax (159 us, 1.4% occupancy, latency-bound) removed.
// Softmax over m is computed max-free (|S|<=64 << 88 overflow bound):
//   colsum: invZ[b][n] = 1/sum_m exp(S[m][n])   (read-only, 256 blocks)
//   tp:     A = exp(S) staged on the fly, invZ folded into the Tm stage.
// Everything else identical to round 5 (passing, absmax 1.14e-5).
// ---------------------------------------------------------------------------

#define DEVI static __device__ __forceinline__
typedef __attribute__((ext_vector_type(8))) short short8;
typedef __attribute__((ext_vector_type(4))) float f32x4;
typedef unsigned short ushort_t;

DEVI float fsig(float x)   { return 1.f / (1.f + __expf(-x)); }
DEVI float ftanh_(float x) { return 2.f / (1.f + __expf(-2.f * x)) - 1.f; }
DEVI float bf2f(ushort_t u) { union { unsigned int i; float f; } v; v.i = ((unsigned int)u) << 16; return v.f; }
DEVI ushort_t f2bf(float f) {
    union { float f; unsigned int i; } v; v.f = f;
    unsigned int r = v.i + 0x7FFF + ((v.i >> 16) & 1);
    return (ushort_t)(r >> 16);
}

// ---------------- pack: x0c[nl][t][c] (fp32) --------------------------------
__global__ void pack_kernel(const float* __restrict__ ev,
                            const float* __restrict__ tmpl,
                            float* __restrict__ x0, int n0)
{
    const int nl = blockIdx.z;
    const int n  = n0 + nl;
    const int t0 = blockIdx.x * 32;
    const int c0 = blockIdx.y * 32;
    const float* src = (n < 16) ? (ev + n * 65536) : (tmpl + (n - 16) * 65536);
    __shared__ float tile[32][33];
    const int tx = threadIdx.x, ty = threadIdx.y;
#pragma unroll
    for (int k = 0; k < 4; k++) {
        int cl = ty + 8 * k;
        tile[cl][tx] = src[(c0 + cl) * 512 + t0 + tx];
    }
    __syncthreads();
#pragma unroll
    for (int k = 0; k < 4; k++) {
        int tl = ty + 8 * k;
        x0[(nl * 512 + t0 + tl) * 128 + c0 + tx] = tile[tx][tl];
    }
}

// ---------------- weight packs ---------------------------------------------
__global__ void pack_w2(const float* __restrict__ w2, ushort_t* __restrict__ w2p)
{
    for (int idx = blockIdx.x * 256 + threadIdx.x; idx < 15360; idx += gridDim.x * 256) {
        int kh = idx / 3072, rem = idx % 3072;
        int kw = rem / 512;
        int co = (rem >> 4) & 31, ci = rem & 15;
        float v = (kw < 5) ? w2[((co * 16 + ci) * 5 + kh) * 5 + kw] : 0.f;
        w2p[idx] = f2bf(v);
    }
}
__global__ void pack_w3(const float* __restrict__ w3, ushort_t* __restrict__ w3p)
{
    for (int idx = blockIdx.x * 256 + threadIdx.x; idx < 51200; idx += gridDim.x * 256) {
        int kh = idx / 10240, rem = idx % 10240;
        int kw = rem / 2048;
        int co = (rem >> 5) & 63, ci = rem & 31;
        w3p[idx] = f2bf(w3[((co * 32 + ci) * 5 + kh) * 5 + kw]);
    }
}
__global__ void pack_l1w(const float* __restrict__ l1w, ushort_t* __restrict__ l1wp)
{
    for (int idx = blockIdx.x * 256 + threadIdx.x; idx < 262144; idx += gridDim.x * 256) {
        int n = idx >> 12, kp = idx & 4095;
        int r = kp >> 6, j = kp & 63;
        float v = (j < 58) ? l1w[n * 3712 + r * 58 + j] : 0.f;
        l1wp[idx] = f2bf(v);
    }
}

// ---------------- conv1: fp32 direct, CI=1, writes NHWC bf16 ---------------
__global__ void conv1_kernel(const float* __restrict__ in,
                             const float* __restrict__ wgt,
                             const float* __restrict__ bias,
                             ushort_t* __restrict__ out)
{
    const int h0  = blockIdx.x * 4;
    const int w0  = blockIdx.y * 62;
    const int nl  = blockIdx.z;
    const int tid = threadIdx.x;
    const int wl  = tid & 63;
    const int cg  = tid >> 6;

    __shared__ float tin[8 * 68];
    __shared__ float tw[16 * 25];

    float acc[4][4];
#pragma unroll
    for (int j = 0; j < 4; j++)
#pragma unroll
        for (int hh = 0; hh < 4; hh++) acc[j][hh] = 0.f;

    const float* ibase = in + (nl * 512 + h0) * 128 + w0;
    for (int idx = tid; idx < 8 * 66; idx += 256) {
        int r = idx / 66, cc = idx - r * 66;
        tin[r * 68 + cc] = ibase[r * 128 + cc];
    }
    for (int idx = tid; idx < 400; idx += 256) tw[idx] = wgt[idx];
    __syncthreads();
#pragma unroll
    for (int kh = 0; kh < 5; kh++) {
#pragma unroll
        for (int kw = 0; kw < 5; kw++) {
            float iv[4];
#pragma unroll
            for (int hh = 0; hh < 4; hh++)
                iv[hh] = tin[(hh + kh) * 68 + wl + kw];
#pragma unroll
            for (int j = 0; j < 4; j++) {
                float wv = tw[(cg * 4 + j) * 25 + kh * 5 + kw];
#pragma unroll
                for (int hh = 0; hh < 4; hh++)
                    acc[j][hh] = fmaf(wv, iv[hh], acc[j][hh]);
            }
        }
    }
    if (wl < 62) {
#pragma unroll
        for (int hh = 0; hh < 4; hh++) {
            ushort_t pk[4];
#pragma unroll
            for (int j = 0; j < 4; j++)
                pk[j] = f2bf(acc[j][hh] + bias[cg * 4 + j]);
            ushort_t* dst = out + ((size_t)(nl * 508 + h0 + hh) * 124 + w0 + wl) * 16 + cg * 4;
            *(uint2*)dst = *(uint2*)pk;
        }
    }
}

// ---------------- MFMA implicit-GEMM 5x5 conv (conflict-free LDS) ----------
template<int CI, int CO, int NF, int MF, int W_T, int KSTEPS, int KW_TOT,
         int H_IN, int W_IN, bool PAD2>
__global__ __launch_bounds__(256, 4) void conv_mfma(
    const ushort_t* __restrict__ in, const ushort_t* __restrict__ wpk,
    const float* __restrict__ bias, ushort_t* __restrict__ out)
{
    constexpr int H_OUT = H_IN - 4;
    constexpr int W_OUT = W_IN - 4;
    constexpr int HALO  = W_T + 6;
    constexpr int OCT   = CI / 8;
    constexpr int APL   = 8 * HALO;
    constexpr int BPL   = KW_TOT * CO;

    const int h0 = blockIdx.x * 4;
    const int w0 = blockIdx.y * W_T;
    const int nl = blockIdx.z;
    const int tid  = threadIdx.x;
    const int wv   = tid >> 6;
    const int lane = tid & 63;
    const int l16  = lane & 15;
    const int kq   = lane >> 4;

    __shared__ __align__(16) ushort_t As[OCT * APL * 8];
    __shared__ __align__(16) ushort_t Bs[OCT * BPL * 8];

    f32x4 acc[MF][NF];
#pragma unroll
    for (int mi = 0; mi < MF; mi++)
#pragma unroll
        for (int ni = 0; ni < NF; ni++) acc[mi][ni] = f32x4{0.f, 0.f, 0.f, 0.f};

    for (int idx = tid; idx < OCT * APL; idx += 256) {
        int oct = idx / APL, e = idx - oct * APL;
        int r = e / HALO, c = e - r * HALO;
        const ushort_t* src = in + ((size_t)((nl * H_IN + h0 + r) * W_IN + w0 + c)) * CI + oct * 8;
        *(short8*)&As[idx * 8] = *(const short8*)src;
    }

    const int aoct = PAD2 ? (kq & 1) : kq;
    const int kwq  = PAD2 ? (kq >> 1) : 0;

#pragma unroll
    for (int kh = 0; kh < 5; kh++) {
        __syncthreads();
        for (int idx = tid; idx < OCT * BPL; idx += 256) {
            int oct = idx / BPL, e = idx - oct * BPL;
            int kw = e / CO, co = e - kw * CO;
            const ushort_t* src = wpk + ((size_t)((kh * KW_TOT + kw) * CO + co)) * CI + oct * 8;
            *(short8*)&Bs[idx * 8] = *(const short8*)src;
        }
        __syncthreads();
#pragma unroll
        for (int st = 0; st < KSTEPS; st++) {
            int colq = (PAD2 ? st * 2 : st) + kwq;
            short8 af[MF], bfv[NF];
#pragma unroll
            for (int mi = 0; mi < MF; mi++)
                af[mi] = *(const short8*)&As[(aoct * APL + (wv + kh) * HALO + mi * 16 + l16 + colq) * 8];
#pragma unroll
            for (int ni = 0; ni < NF; ni++)
                bfv[ni] = *(const short8*)&Bs[(aoct * BPL + colq * CO + ni * 16 + l16) * 8];
#pragma unroll
            for (int mi = 0; mi < MF; mi++)
#pragma unroll
                for (int ni = 0; ni < NF; ni++)
                    acc[mi][ni] = __builtin_amdgcn_mfma_f32_16x16x32_bf16(
                        af[mi], bfv[ni], acc[mi][ni], 0, 0, 0);
        }
    }

    const int h = h0 + wv;
#pragma unroll
    for (int mi = 0; mi < MF; mi++) {
#pragma unroll
        for (int ni = 0; ni < NF; ni++) {
            int co = ni * 16 + l16;
            float bv = bias[co];
#pragma unroll
            for (int reg = 0; reg < 4; reg++) {
                int w = w0 + mi * 16 + kq * 4 + reg;
                if (w < W_OUT)
                    out[((size_t)(nl * H_OUT + h) * W_OUT + w) * CO + co] =
                        f2bf(acc[mi][ni][reg] + bv);
            }
        }
    }
}

// ---------------- pool pass 1: max over (5 rows x 2 cols), 8 s-chunks ------
__global__ void pool_vh(const ushort_t* __restrict__ a3, ushort_t* __restrict__ v2)
{
    const int nl = blockIdx.z;
    const int sc = blockIdx.y;           // 8 chunks of 62
    const int g  = blockIdx.x * 256 + threadIdx.x;
    if (g >= 3712) return;
    const int j = g >> 6, c = g & 63;
    const ushort_t* base = a3 + (size_t)nl * 500 * 116 * 64 + (size_t)(2 * j) * 64 + c;
    const int s0 = sc * 62;
    float rm[5];
#pragma unroll
    for (int r = 0; r < 4; r++) {
        float a = bf2f(base[(size_t)(s0 + r) * 7424]);
        float b = bf2f(base[(size_t)(s0 + r) * 7424 + 64]);
        rm[r] = fmaxf(a, b);
    }
    rm[4] = -1e30f;
    int slot = 4;
    for (int s = s0; s < s0 + 62; s++) {
        int rr = s + 4;
        float a = bf2f(base[(size_t)rr * 7424]);
        float b = bf2f(base[(size_t)rr * 7424 + 64]);
        rm[slot] = fmaxf(a, b);
        slot = (slot == 4) ? 0 : slot + 1;
        float m = fmaxf(fmaxf(fmaxf(rm[0], rm[1]), fmaxf(rm[2], rm[3])), rm[4]);
        v2[((size_t)(nl * 496 + s) * 58 + j) * 64 + c] = f2bf(m);
    }
}

// ---------------- pool pass 2: (s,j,c) -> NCHW-flat pooled[c][s][j] --------
__global__ void pool_tr(const ushort_t* __restrict__ v2, ushort_t* __restrict__ pooled)
{
    const int nl = blockIdx.y;
    const int s0 = blockIdx.x * 2;
    const int t  = threadIdx.x;
    __shared__ ushort_t Li[2 * 58 * 64];
    __shared__ ushort_t Lo[64 * 116];
    const ushort_t* src = v2 + (size_t)(nl * 496 + s0) * 58 * 64;
    for (int i = t; i < 928; i += 256)
        *(short8*)&Li[i * 8] = *(const short8*)&src[i * 8];
    __syncthreads();
    {
        const int c = t & 63, q = t >> 6;
        const int s = q & 1, jh = q >> 1;
#pragma unroll
        for (int jj = 0; jj < 29; jj++) {
            int j = jh * 29 + jj;
            Lo[c * 116 + s * 58 + j] = Li[(s * 58 + j) * 64 + c];
        }
    }
    __syncthreads();
    ushort_t* dst = pooled + (size_t)nl * 1841152;
    for (int i = t; i < 7424; i += 256) {
        int c = i / 116, rem = i - c * 116;
        dst[(size_t)c * 28768 + s0 * 58 + rem] = Lo[i];
    }
}

// ---------------- lin1: M=64 N=64 K=1024/block MFMA, k-split x4 ------------
__global__ __launch_bounds__(256) void lin1_mfma(
    const ushort_t* __restrict__ pooled, const ushort_t* __restrict__ l1wp,
    float* __restrict__ xb, int n0, int RT)
{
    const int mt  = blockIdx.x;
    const int kqb = blockIdx.y;          // 4 k-quarters
    const int r0  = mt * 64;
    const int t   = threadIdx.x;
    const int wv  = t >> 6, lane = t & 63, l16 = lane & 15, kq = lane >> 4;

    __shared__ __align__(16) ushort_t As[8 * 64 * 8];  // [oct][row]
    __shared__ __align__(16) ushort_t Bs[8 * 64 * 8];  // [oct][co]

    f32x4 acc[4];
#pragma unroll
    for (int ni = 0; ni < 4; ni++) acc[ni] = f32x4{0.f, 0.f, 0.f, 0.f};

    for (int kb = 0; kb < 16; kb++) {
        const int k0 = kqb * 1024 + kb * 64;
        const int r  = k0 >> 6;
        __syncthreads();
        for (int idx = t; idx < 512; idx += 256) {
            int oct = idx >> 6, row = idx & 63;
            int rr = r0 + row;
            short8 v = short8{0, 0, 0, 0, 0, 0, 0, 0};
            if (rr < RT)
                v = *(const short8*)(pooled + (size_t)rr * 3712 + r * 58 + oct * 8);
            *(short8*)&As[idx * 8] = v;
        }
        for (int idx = t; idx < 512; idx += 256) {
            int oct = idx >> 6, co = idx & 63;
            *(short8*)&Bs[idx * 8] =
                *(const short8*)(l1wp + (size_t)co * 4096 + k0 + oct * 8);
        }
        __syncthreads();
#pragma unroll
        for (int st = 0; st < 2; st++) {
            short8 af = *(const short8*)&As[((st * 4 + kq) * 64 + wv * 16 + l16) * 8];
#pragma unroll
            for (int ni = 0; ni < 4; ni++) {
                short8 bfv = *(const short8*)&Bs[((st * 4 + kq) * 64 + ni * 16 + l16) * 8];
                acc[ni] = __builtin_amdgcn_mfma_f32_16x16x32_bf16(af, bfv, acc[ni], 0, 0, 0);
            }
        }
    }
#pragma unroll
    for (int ni = 0; ni < 4; ni++) {
        int co = ni * 16 + l16;
#pragma unroll
        for (int reg = 0; reg < 4; reg++) {
            int rr = r0 + wv * 16 + kq * 4 + reg;
            if (rr < RT)
                atomicAdd(&xb[((size_t)n0 * 496 + rr) * 64 + co], acc[ni][reg]);
        }
    }
}

// ---------------- gi = (x + l1b) @ W_ih^T + b_ih ---------------------------
__global__ void gi_kernel(const float* __restrict__ x,
                          const float* __restrict__ Wih,
                          const float* __restrict__ bih,
                          const float* __restrict__ l1b,
                          float* __restrict__ gi)
{
    const int r0 = blockIdx.x * 16;
    const int j  = threadIdx.x; // 192 threads
    __shared__ float xl[16 * 64];
    float w[64];
#pragma unroll
    for (int d = 0; d < 64; d++) w[d] = Wih[j * 64 + d];
    const float bj = bih[j];
    for (int idx = j; idx < 1024; idx += 192)
        xl[idx] = x[r0 * 64 + idx] + l1b[idx & 63];
    __syncthreads();
    for (int s = 0; s < 16; s++) {
        float a = bj;
#pragma unroll
        for (int d = 0; d < 64; d++) a = fmaf(w[d], xl[s * 64 + d], a);
        gi[(size_t)(r0 + s) * 192 + j] = a;
    }
}

// ---------------- chunk-parallel GRU (fp32, unchanged) ---------------------
__global__ __launch_bounds__(64, 1) void gru_kernel(
    const float* __restrict__ gi, const float* __restrict__ Whh,
    const float* __restrict__ bhh, float* __restrict__ Eo,
    float* __restrict__ To)
{
    const int c  = blockIdx.x;
    const int br = c >> 8;
    const int q  = c & 255;
    const int i  = threadIdx.x;
    const float* gb = gi + (size_t)br * 7936 * 192;
    float* out = br ? To : Eo;

    float wr[64], wz[64], wn[64];
#pragma unroll
    for (int k = 0; k < 64; k++) wr[k] = Whh[i * 64 + k];
#pragma unroll
    for (int k = 0; k < 64; k++) wz[k] = Whh[(64 + i) * 64 + k];
#pragma unroll
    for (int k = 0; k < 64; k++) wn[k] = Whh[(128 + i) * 64 + k];
    const float bhr = bhh[i], bhz = bhh[64 + i], bhn = bhh[128 + i];

    __shared__ __align__(16) float hs[64];
    float h[64];
#pragma unroll
    for (int k = 0; k < 64; k++) h[k] = 0.f;
    float hown = 0.f;

    const int cs  = q * 31;
    int start = cs - 96;
    if (start < 0) start = 0;
    const int end = cs + 31;

    float pr[4], pz[4], pn[4];
#pragma unroll
    for (int u = 0; u < 4; u++) {
        int s = start + u;
        if (s < end) {
            const float* g = gb + (size_t)s * 192;
            pr[u] = g[i]; pz[u] = g[64 + i]; pn[u] = g[128 + i];
        } else { pr[u] = 0.f; pz[u] = 0.f; pn[u] = 0.f; }
    }

    int s = start;
    while (s < end) {
#pragma unroll
        for (int u = 0; u < 4; u++) {
            if (s < end) {
                float gr = pr[u], gz = pz[u], gn = pn[u];
                int sp = s + 4;
                if (sp < end) {
                    const float* g = gb + (size_t)sp * 192;
                    pr[u] = g[i]; pz[u] = g[64 + i]; pn[u] = g[128 + i];
                }
                float ar = bhr, az = bhz, an = bhn;
#pragma unroll
                for (int k = 0; k < 64; k++) {
                    ar = fmaf(wr[k], h[k], ar);
                    az = fmaf(wz[k], h[k], az);
                    an = fmaf(wn[k], h[k], an);
                }
                float r  = fsig(gr + ar);
                float z  = fsig(gz + az);
                float nv = ftanh_(gn + r * an);
                float hn = (1.f - z) * nv + z * hown;
                hown = hn;
                hs[i] = hn;
                __syncthreads();
#pragma unroll
                for (int k = 0; k < 16; k++) {
                    float4 v = ((const float4*)hs)[k];
                    h[4 * k + 0] = v.x; h[4 * k + 1] = v.y;
                    h[4 * k + 2] = v.z; h[4 * k + 3] = v.w;
                }
                __syncthreads();
                if (s >= cs) out[(size_t)s * 64 + i] = hn;
                s++;
            }
        }
    }
}

// ---------------- scores[b][m][n] = E[b][m] . Tm[b][n] (raw) ----------------
__global__ void scores_kernel(const float* __restrict__ E,
                              const float* __restrict__ Tm,
                              float* __restrict__ S)
{
    const int b  = blockIdx.z;
    const int m0 = blockIdx.y * 32;
    const int n0 = blockIdx.x * 64;
    const int t  = threadIdx.x;
    const int nl = t & 63, mg = t >> 6;
    __shared__ float El[32 * 64];
    __shared__ float Tms[64 * 65];

    for (int idx = t; idx < 2048; idx += 256) {
        int r = idx >> 6, d = idx & 63;
        int m = m0 + r;
        El[idx] = (m < 496) ? E[((size_t)b * 496 + m) * 64 + d] : 0.f;
    }
    for (int idx = t; idx < 4096; idx += 256) {
        int r = idx >> 6, d = idx & 63;
        int n = n0 + r;
        Tms[d * 65 + r] = (n < 496) ? Tm[((size_t)b * 496 + n) * 64 + d] : 0.f;
    }
    __syncthreads();

    float acc[8];
#pragma unroll
    for (int j = 0; j < 8; j++) acc[j] = 0.f;
#pragma unroll 4
    for (int d = 0; d < 64; d++) {
        float tv = Tms[d * 65 + nl];
#pragma unroll
        for (int j = 0; j < 8; j++)
            acc[j] = fmaf(El[(mg * 8 + j) * 64 + d], tv, acc[j]);
    }
    int n = n0 + nl;
    if (n < 496) {
#pragma unroll
        for (int j = 0; j < 8; j++) {
            int m = m0 + mg * 8 + j;
            if (m < 496) S[((size_t)b * 496 + m) * 496 + n] = acc[j];
        }
    }
}

// ---------------- colsum: invZ[b][n] = 1 / sum_m exp(S[b][m][n]) -----------
__global__ void colsum_kernel(const float* __restrict__ S,
                              float* __restrict__ invZ)
{
    const int b  = blockIdx.y;
    const int n0 = blockIdx.x * 32;      // 16 tiles x 32 cols
    const int t  = threadIdx.x;          // 256
    const int c  = t & 31, rg = t >> 5;  // 8 row-groups of 62
    const int n  = n0 + c;
    float sum = 0.f;
    if (n < 496) {
        const float* base = S + (size_t)b * 246016 + n;
        for (int mm = rg * 62; mm < rg * 62 + 62; mm++)
            sum += __expf(base[(size_t)mm * 496]);
    }
    __shared__ float red[256];
    red[t] = sum;
    __syncthreads();
    if (t < 32) {
        float s = 0.f;
#pragma unroll
        for (int g = 0; g < 8; g++) s += red[g * 32 + t];
        if (n0 + t < 496) invZ[b * 496 + n0 + t] = 1.f / s;
    }
}

// ---------------- Tp[m][d] = sum_n exp(S[m][n]) * invZ[n] * Tm[n][d] -------
__global__ void tp_kernel(const float* __restrict__ S,
                          const float* __restrict__ Tm,
                          const float* __restrict__ invZ,
                          float* __restrict__ Tp)
{
    const int b  = blockIdx.y;
    const int m0 = blockIdx.x * 32;
    const int t  = threadIdx.x;
    const int d  = t & 63, mg = t >> 6;
    __shared__ float As2[32 * 128];
    __shared__ float Ts[128 * 64];
    float acc[8];
#pragma unroll
    for (int j = 0; j < 8; j++) acc[j] = 0.f;

    for (int nc = 0; nc < 512; nc += 128) {
        __syncthreads();
        for (int idx = t; idx < 4096; idx += 256) {
            int r = idx >> 7, cc = idx & 127;
            int m = m0 + r, n = nc + cc;
            As2[idx] = (m < 496 && n < 496)
                          ? __expf(S[((size_t)b * 496 + m) * 496 + n]) : 0.f;
        }
        for (int idx = t; idx < 8192; idx += 256) {
            int r = idx >> 6, dd = idx & 63;
            int n = nc + r;
            Ts[idx] = (n < 496)
                          ? Tm[((size_t)b * 496 + n) * 64 + dd] * invZ[b * 496 + n]
                          : 0.f;
        }
        __syncthreads();
#pragma unroll 4
        for (int nn = 0; nn < 128; nn++) {
            float tv = Ts[nn * 64 + d];
#pragma unroll
            for (int j = 0; j < 8; j++)
                acc[j] = fmaf(As2[(mg * 8 + j) * 128 + nn], tv, acc[j]);
        }
    }
#pragma unroll
    for (int j = 0; j < 8; j++) {
        int m = m0 + mg * 8 + j;
        if (m < 496) Tp[((size_t)b * 496 + m) * 64 + d] = acc[j];
    }
}

// ---------------- att softmax + rep ----------------------------------------
__global__ void attrep_kernel(const float* __restrict__ E,
                              const float* __restrict__ Tp,
                              const float* __restrict__ attw,
                              const float* __restrict__ attb,
                              float* __restrict__ rep)
{
    const int b = blockIdx.x;
    const int t = threadIdx.x; // 256
    __shared__ float aw[64];
    __shared__ float lg[496];
    __shared__ float att[496];
    __shared__ float redm[4], reds[4];
    __shared__ float part[256];

    if (t < 64) aw[t] = attw[t];
    __syncthreads();
    for (int s = t; s < 496; s += 256) {
        const float* Er = E + ((size_t)b * 496 + s) * 64;
        float a = 0.f;
#pragma unroll
        for (int dd = 0; dd < 64; dd++) a = fmaf(Er[dd], aw[dd], a);
        lg[s] = a + attb[0];
    }
    __syncthreads();
    float m = -1e30f;
    for (int s = t; s < 496; s += 256) m = fmaxf(m, lg[s]);
    for (int off = 32; off > 0; off >>= 1)
        m = fmaxf(m, __shfl_xor(m, off, 64));
    if ((t & 63) == 0) redm[t >> 6] = m;
    __syncthreads();
    m = fmaxf(fmaxf(redm[0], redm[1]), fmaxf(redm[2], redm[3]));
    float sum = 0.f;
    for (int s = t; s < 496; s += 256) {
        float e = __expf(lg[s] - m);
        att[s] = e;
        sum += e;
    }
    for (int off = 32; off > 0; off >>= 1) sum += __shfl_xor(sum, off, 64);
    if ((t & 63) == 0) reds[t >> 6] = sum;
    __syncthreads();
    float inv = 1.f / (reds[0] + reds[1] + reds[2] + reds[3]);

    const int d = t & 63, sg = t >> 6;
    float p = 0.f;
    for (int k = 0; k < 124; k++) {
        int s = sg + 4 * k;
        size_t o = ((size_t)b * 496 + s) * 64 + d;
        p = fmaf(att[s] * inv, fabsf(Tp[o] - E[o]), p);
    }
    part[t] = p;
    __syncthreads();
    if (t < 64)
        rep[b * 64 + t] = part[t] + part[64 + t] + part[128 + t] + part[192 + t];
}

// ---------------- tail MLP --------------------------------------------------
__global__ void mlp_kernel(const float* __restrict__ rep,
                           const float* __restrict__ W3,
                           const float* __restrict__ b3,
                           const float* __restrict__ Wc,
                           const float* __restrict__ bc,
                           float* __restrict__ out)
{
    const int b = blockIdx.x;
    const int t = threadIdx.x; // 128
    __shared__ float hr[64];
    __shared__ float h2[128];
    if (t < 64) hr[t] = fmaxf(rep[b * 64 + t], 0.f);
    __syncthreads();
    float a = b3[t];
#pragma unroll
    for (int d = 0; d < 64; d++) a = fmaf(W3[t * 64 + d], hr[d], a);
    h2[t] = fmaxf(a, 0.f);
    __syncthreads();
    if (t < 2) {
        float o = bc[t];
        for (int k = 0; k < 128; k++) o = fmaf(Wc[t * 128 + k], h2[k], o);
        out[b * 2 + t] = o;
    }
}

// ---------------------------------------------------------------------------
extern "C" void kernel_launch(void* const* d_in, const int* in_sizes, int n_in,
                              void* d_out, int out_size, void* d_ws,
                              size_t ws_size, hipStream_t stream)
{
    const float* ev   = (const float*)d_in[0];
    const float* tmpl = (const float*)d_in[1];
    const float* w1   = (const float*)d_in[2];
    const float* b1   = (const float*)d_in[3];
    const float* w2   = (const float*)d_in[4];
    const float* b2   = (const float*)d_in[5];
    const float* w3   = (const float*)d_in[6];
    const float* b3   = (const float*)d_in[7];
    const float* l1w  = (const float*)d_in[8];
    const float* l1b  = (const float*)d_in[9];
    const float* wih  = (const float*)d_in[10];
    const float* whh  = (const float*)d_in[11];
    const float* bih  = (const float*)d_in[12];
    const float* bhh  = (const float*)d_in[13];
    const float* attw = (const float*)d_in[14];
    const float* attb = (const float*)d_in[15];
    const float* l3w  = (const float*)d_in[16];
    const float* l3b  = (const float*)d_in[17];
    const float* clw  = (const float*)d_in[18];
    const float* clb  = (const float*)d_in[19];

    // ---- persistent region (float units) ----
    float* ws = (float*)d_ws;
    float* xb    = ws;                         // 1,015,808
    float* Eb    = xb + 1015808ull;            // 507,904
    float* Tb    = Eb + 507904ull;
    float* Tpb   = Tb + 507904ull;
    float* repb  = Tpb + 507904ull;            // 1,024
    float* w2pf  = repb + 1024ull;             // 7,680 (15,360 bf16)
    float* w3pf  = w2pf + 7680ull;             // 25,600 (51,200 bf16)
    float* l1wpf = w3pf + 25600ull;            // 131,072 (262,144 bf16)
    float* invZb = l1wpf + 131072ull;          // 8,192 (16 x 496 used)
    float* arena = invZb + 8192ull;
    const size_t PERSIST = 2713088ull;

    ushort_t* w2p  = (ushort_t*)w2pf;
    ushort_t* w3p  = (ushort_t*)w3pf;
    ushort_t* l1wp = (ushort_t*)l1wpf;

    // ---- chunk size selection ----
    const int cand[6] = {32, 16, 8, 4, 2, 1};
    int C = 0;
    for (int ci = 0; ci < 6; ci++) {
        size_t a = (size_t)cand[ci] * 2823680ull + 4096ull;
        if (a < 3936256ull) a = 3936256ull;
        if ((PERSIST + a) * sizeof(float) <= ws_size) { C = cand[ci]; break; }
    }
    if (C == 0) return;

    float*    S1 = arena;
    float*    S2 = arena + (size_t)C * 967680ull + 2048ull;
    float*    gib = arena;     // 3,047,424 f (after conv phase)
    float*    Sb  = arena;     // 3,936,256 f (after gru)

    float*    x0  = S1;
    ushort_t* a2  = (ushort_t*)S1;
    ushort_t* v2  = (ushort_t*)S1;
    ushort_t* a1  = (ushort_t*)S2;
    ushort_t* a3  = (ushort_t*)S2;
    ushort_t* pooled = (ushort_t*)S2;  // NCHW-flat: C x (64*496*58)

    // ---- weight packs + xb zero ----
    hipMemsetAsync(xb, 0, 1015808ull * sizeof(float), stream);
    pack_w2<<<15, 256, 0, stream>>>(w2, w2p);
    pack_w3<<<50, 256, 0, stream>>>(w3, w3p);
    pack_l1w<<<256, 256, 0, stream>>>(l1w, l1wp);

    const int RT = C * 496;
    const int mtiles = (RT + 63) / 64;

    // ---- conv trunk + pool + lin1, chunked ----
    for (int n0 = 0; n0 < 32; n0 += C) {
        pack_kernel<<<dim3(16, 4, C), dim3(32, 8), 0, stream>>>(ev, tmpl, x0, n0);
        conv1_kernel<<<dim3(127, 2, C), 256, 0, stream>>>(x0, w1, b1, a1);
        conv_mfma<16, 32, 2, 4, 64, 3, 6, 508, 124, true>
            <<<dim3(126, 2, C), 256, 0, stream>>>(a1, w2p, b2, a2);
        conv_mfma<32, 64, 4, 2, 32, 5, 5, 504, 120, false>
            <<<dim3(125, 4, C), 256, 0, stream>>>(a2, w3p, b3, a3);
        pool_vh<<<dim3(15, 8, C), 256, 0, stream>>>(a3, v2);
        pool_tr<<<dim3(248, C), 256, 0, stream>>>(v2, pooled);
        lin1_mfma<<<dim3(mtiles, 4), 256, 0, stream>>>(pooled, l1wp, xb, n0, RT);
    }

    // ---- GRU ----
    gi_kernel<<<992, 192, 0, stream>>>(xb, wih, bih, l1b, gib);
    gru_kernel<<<512, 64, 0, stream>>>(gib, whh, bhh, Eb, Tb);

    // ---- alignment: raw scores -> column sums -> Tp (exp folded in) ----
    scores_kernel<<<dim3(8, 16, 16), 256, 0, stream>>>(Eb, Tb, Sb);
    colsum_kernel<<<dim3(16, 16), 256, 0, stream>>>(Sb, invZb);
    tp_kernel<<<dim3(16, 16), 256, 0, stream>>>(Sb, Tb, invZb, Tpb);

    // ---- attention + tail ----
    attrep_kernel<<<16, 256, 0, stream>>>(Eb, Tpb, attw, attb, repb);
    mlp_kernel<<<16, 128, 0, stream>>>(repb, l3w, l3b, clw, clb,
                                       (float*)d_out);
}